// Round 1
// baseline (149.096 us; speedup 1.0000x reference)
//
#include <hip/hip_runtime.h>

typedef unsigned short u16;
typedef unsigned int u32;
typedef __attribute__((ext_vector_type(8))) short bf16x8;
typedef __attribute__((ext_vector_type(4))) float f32x4;

#define LOG2E 1.4426950408889634f
#define QSCALE (0.125f * LOG2E)

__device__ __forceinline__ u16 f2bf(float f) {
  union { float f; u32 u; } x; x.f = f;
  u32 r = x.u + 0x7fffu + ((x.u >> 16) & 1u);   // RNE; inputs are finite
  return (u16)(r >> 16);
}

__device__ __forceinline__ void gload_lds16(const void* g, void* l) {
  __builtin_amdgcn_global_load_lds((const __attribute__((address_space(1))) u32*)g,
                                   (__attribute__((address_space(3))) u32*)l, 16, 0, 0);
}

// ---------------- prep: fp32 -> bf16 (x), 8 elems/thread ----------------
__global__ __launch_bounds__(256) void k_cvt_x(const float* __restrict__ in, u16* __restrict__ out) {
  int i = blockIdx.x * 256 + threadIdx.x;
  const float4* p = (const float4*)in;
  float4 a = p[i * 2], b = p[i * 2 + 1];
  uint4 o;
  o.x = (u32)f2bf(a.x) | ((u32)f2bf(a.y) << 16);
  o.y = (u32)f2bf(a.z) | ((u32)f2bf(a.w) << 16);
  o.z = (u32)f2bf(b.x) | ((u32)f2bf(b.y) << 16);
  o.w = (u32)f2bf(b.z) | ((u32)f2bf(b.w) << 16);
  ((uint4*)out)[i] = o;
}

// ---------------- prep: transpose + convert: src[R][Cc] f32 -> dst[Cc][R] bf16 ----------------
__global__ __launch_bounds__(256) void k_transpose_cvt(const float* __restrict__ src, u16* __restrict__ dst,
                                                       int R, int Cc) {
  __shared__ float tile[32][33];
  int c0 = blockIdx.x * 32, r0 = blockIdx.y * 32;
  int tx = threadIdx.x, ty = threadIdx.y;   // (32,8)
  #pragma unroll
  for (int j = 0; j < 4; ++j)
    tile[ty * 4 + j][tx] = src[(r0 + ty * 4 + j) * Cc + c0 + tx];
  __syncthreads();
  #pragma unroll
  for (int j = 0; j < 4; ++j) {
    int cl = ty * 4 + j;
    dst[(c0 + cl) * R + r0 + tx] = f2bf(tile[tx][cl]);
  }
}

// ---------------- 128x128 bf16 GEMM core (m97 structure), K=1024, BK=32 ----------------
// A  : [M][1024] bf16 row-major
// Bt : [N][1024] bf16 row-major (transposed weight: Bt[n][k])
// EPI 0: of[m][col] = acc + bias[col]  (fp32, N=ncols)
// EPI 1: qkv scatter: cols [0,1024)->q (scaled), [1024,2048)->k, [2048,3072)->vt (LDS transposed)
template <int EPI>
__global__ __launch_bounds__(256) void k_gemm(const u16* __restrict__ A, const u16* __restrict__ Bt,
                                              const float* __restrict__ bias,
                                              u16* __restrict__ oq, u16* __restrict__ ok,
                                              u16* __restrict__ ovt, float* __restrict__ of, int N) {
  __shared__ u16 lds[EPI ? 17408 : 8192];   // stage: A[128][32]+B[128][32]=8192; EPI1 transpose: 128*136
  const int tid = threadIdx.x;
  const int l = tid & 63, w = tid >> 6;
  const int wm = w >> 1, wn = w & 1;
  const int lr = l & 15, lh = l >> 4;
  const int bm = blockIdx.y, bn = blockIdx.x;
  u16* As = lds;
  u16* Bs = lds + 4096;
  f32x4 acc[4][4] = {};
  const int e = tid * 8;                    // staging element idx; row=e>>5, col=e&31
  const u16* gA = A + (bm * 128 + (e >> 5)) * 1024 + (e & 31);
  const u16* gB = Bt + (bn * 128 + (e >> 5)) * 1024 + (e & 31);

  for (int kk = 0; kk < 1024; kk += 32) {
    __syncthreads();
    gload_lds16(gA + kk,          As + e);
    gload_lds16(gA + kk + 65536,  As + e + 2048);   // +64 rows
    gload_lds16(gB + kk,          Bs + e);
    gload_lds16(gB + kk + 65536,  Bs + e + 2048);
    __syncthreads();
    bf16x8 af[4], bfr[4];
    #pragma unroll
    for (int mi = 0; mi < 4; ++mi)
      af[mi] = *(const bf16x8*)(As + (wm * 64 + mi * 16 + lr) * 32 + lh * 8);
    #pragma unroll
    for (int ni = 0; ni < 4; ++ni)
      bfr[ni] = *(const bf16x8*)(Bs + (wn * 64 + ni * 16 + lr) * 32 + lh * 8);
    #pragma unroll
    for (int mi = 0; mi < 4; ++mi)
      #pragma unroll
      for (int ni = 0; ni < 4; ++ni)
        acc[mi][ni] = __builtin_amdgcn_mfma_f32_16x16x32_bf16(af[mi], bfr[ni], acc[mi][ni], 0, 0, 0);
  }

  if (EPI == 0) {
    #pragma unroll
    for (int ni = 0; ni < 4; ++ni) {
      int col = bn * 128 + wn * 64 + ni * 16 + lr;
      float bb = bias[col];
      #pragma unroll
      for (int mi = 0; mi < 4; ++mi) {
        int row = bm * 128 + wm * 64 + mi * 16 + lh * 4;
        #pragma unroll
        for (int r = 0; r < 4; ++r)
          of[(row + r) * N + col] = acc[mi][ni][r] + bb;
      }
    }
  } else {
    int s = bn >> 3;   // 1024-aligned thirds (bn in [0,24))
    if (s < 2) {
      u16* dst = (s == 0) ? oq : ok;
      const float sc = (s == 0) ? QSCALE : 1.0f;
      #pragma unroll
      for (int ni = 0; ni < 4; ++ni) {
        int c = bn * 128 + wn * 64 + ni * 16 + lr;
        float bb = bias[c];
        int cc = c & 1023, h = cc >> 6, d = cc & 63;
        #pragma unroll
        for (int mi = 0; mi < 4; ++mi) {
          int rowb = bm * 128 + wm * 64 + mi * 16 + lh * 4;
          #pragma unroll
          for (int r = 0; r < 4; ++r) {
            int m = rowb + r, b = m >> 10, n = m & 1023;
            dst[((b * 16 + h) * 1024 + n) * 64 + d] = f2bf((acc[mi][ni][r] + bb) * sc);
          }
        }
      }
    } else {
      // v: transpose 128x128 tile via LDS (stride 136), write [bh][d][n] coalesced
      __syncthreads();
      #pragma unroll
      for (int ni = 0; ni < 4; ++ni) {
        int cl = wn * 64 + ni * 16 + lr;
        float bb = bias[bn * 128 + cl];
        #pragma unroll
        for (int mi = 0; mi < 4; ++mi) {
          int rl = wm * 64 + mi * 16 + lh * 4;
          u32 p0 = (u32)f2bf(acc[mi][ni][0] + bb) | ((u32)f2bf(acc[mi][ni][1] + bb) << 16);
          u32 p1 = (u32)f2bf(acc[mi][ni][2] + bb) | ((u32)f2bf(acc[mi][ni][3] + bb) << 16);
          uint2 pk; pk.x = p0; pk.y = p1;
          *(uint2*)(lds + cl * 136 + rl) = pk;
        }
      }
      __syncthreads();
      int cl = tid >> 1, half = tid & 1;
      int c = bn * 128 + cl, cc = c & 1023, h = cc >> 6, d = cc & 63;
      int b = (bm * 128) >> 10, n0 = (bm * 128) & 1023;
      const u16* srow = lds + cl * 136 + half * 64;
      u16* drow = ovt + ((b * 16 + h) * 64 + d) * 1024 + n0 + half * 64;
      #pragma unroll
      for (int j = 0; j < 8; ++j)
        *(uint4*)(drow + j * 8) = *(const uint4*)(srow + j * 8);
    }
  }
}

// ---------------- flash attention: 1 block = (bh, 64-row q-block), 4 waves x 16 rows ----------------
// q,k: [bh][n][64] bf16 (q pre-scaled by 0.125*log2e); vt: [bh][64][n] bf16; ao: [b][n][h*64+d] bf16
__global__ __launch_bounds__(256) void k_attn(const u16* __restrict__ q, const u16* __restrict__ k,
                                              const u16* __restrict__ vt, u16* __restrict__ ao) {
  __shared__ u16 Ks[4096], Vs[4096], Ps[4096];
  const int tid = threadIdx.x, l = tid & 63, w = tid >> 6;
  const int lr = l & 15, lh = l >> 4;
  const int bh = blockIdx.x >> 4, qb = blockIdx.x & 15;

  const u16* qg = q + bh * 65536 + (qb * 64 + w * 16) * 64;
  bf16x8 qa[2];
  qa[0] = *(const bf16x8*)(qg + lr * 64 + lh * 8);
  qa[1] = *(const bf16x8*)(qg + lr * 64 + lh * 8 + 32);

  float mr[4], lsum[4];
  f32x4 o[4] = {};
  #pragma unroll
  for (int r = 0; r < 4; ++r) { mr[r] = -1e30f; lsum[r] = 0.f; }

  const u16* kg = k + bh * 65536;
  const u16* vg = vt + bh * 65536;

  for (int t = 0; t < 16; ++t) {
    __syncthreads();
    #pragma unroll
    for (int j = 0; j < 2; ++j) {
      int chunk = j * 256 + tid;          // 16B chunks; wave-uniform base + lane*16
      int row = chunk >> 3, sub = chunk & 7;
      int gsub = sub ^ (row & 7);          // pre-swizzled global source (m173 pattern)
      gload_lds16(kg + t * 4096 + row * 64 + gsub * 8, Ks + chunk * 8);
      gload_lds16(vg + row * 1024 + t * 64 + gsub * 8, Vs + chunk * 8);   // vt rows stride 1024
    }
    __syncthreads();

    // S = q @ k^T  (scores already in log2 domain via QSCALE)
    f32x4 sv[4] = {};
    #pragma unroll
    for (int ni = 0; ni < 4; ++ni) {
      int row = ni * 16 + lr;
      #pragma unroll
      for (int kt = 0; kt < 2; ++kt) {
        int off = (row * 128 + lh * 16 + kt * 64) ^ ((row & 7) << 4);
        bf16x8 kf = *(const bf16x8*)((const char*)Ks + off);
        sv[ni] = __builtin_amdgcn_mfma_f32_16x16x32_bf16(qa[kt], kf, sv[ni], 0, 0, 0);
      }
    }

    // online softmax (rows live on 16 lanes of same lh group)
    float al[4];
    #pragma unroll
    for (int r = 0; r < 4; ++r) {
      float m0 = fmaxf(fmaxf(sv[0][r], sv[1][r]), fmaxf(sv[2][r], sv[3][r]));
      m0 = fmaxf(m0, __shfl_xor(m0, 1, 16));
      m0 = fmaxf(m0, __shfl_xor(m0, 2, 16));
      m0 = fmaxf(m0, __shfl_xor(m0, 4, 16));
      m0 = fmaxf(m0, __shfl_xor(m0, 8, 16));
      float nm = fmaxf(mr[r], m0);
      al[r] = __builtin_amdgcn_exp2f(mr[r] - nm);
      mr[r] = nm;
    }
    #pragma unroll
    for (int ni = 0; ni < 4; ++ni)
      #pragma unroll
      for (int r = 0; r < 4; ++r)
        sv[ni][r] = __builtin_amdgcn_exp2f(sv[ni][r] - mr[r]);
    #pragma unroll
    for (int r = 0; r < 4; ++r) {
      float s0 = (sv[0][r] + sv[1][r]) + (sv[2][r] + sv[3][r]);
      s0 += __shfl_xor(s0, 1, 16);
      s0 += __shfl_xor(s0, 2, 16);
      s0 += __shfl_xor(s0, 4, 16);
      s0 += __shfl_xor(s0, 8, 16);
      lsum[r] = lsum[r] * al[r] + s0;
    }
    #pragma unroll
    for (int dt = 0; dt < 4; ++dt)
      #pragma unroll
      for (int r = 0; r < 4; ++r)
        o[dt][r] *= al[r];

    // P -> LDS (wave-private, rotation swizzle: conflict-lite writes, aligned 16B reads)
    #pragma unroll
    for (int ni = 0; ni < 4; ++ni) {
      int col = ni * 16 + lr;
      #pragma unroll
      for (int r = 0; r < 4; ++r) {
        int row = lh * 4 + r;
        int off = row * 128 + ((col * 2 + row * 16) & 127);
        *(u16*)((char*)Ps + w * 2048 + off) = f2bf(sv[ni][r]);
      }
    }
    bf16x8 pa[2];
    #pragma unroll
    for (int kt = 0; kt < 2; ++kt) {
      int off = lr * 128 + (((lh * 8 + kt * 32) * 2 + lr * 16) & 127);
      pa[kt] = *(const bf16x8*)((const char*)Ps + w * 2048 + off);
    }
    // O += P @ V
    #pragma unroll
    for (int dt = 0; dt < 4; ++dt) {
      int row = dt * 16 + lr;
      #pragma unroll
      for (int kt = 0; kt < 2; ++kt) {
        int off = (row * 128 + lh * 16 + kt * 64) ^ ((row & 7) << 4);
        bf16x8 vf = *(const bf16x8*)((const char*)Vs + off);
        o[dt] = __builtin_amdgcn_mfma_f32_16x16x32_bf16(pa[kt], vf, o[dt], 0, 0, 0);
      }
    }
  }

  const int b = bh >> 4, h = bh & 15;
  #pragma unroll
  for (int dt = 0; dt < 4; ++dt)
    #pragma unroll
    for (int r = 0; r < 4; ++r) {
      int row = qb * 64 + w * 16 + lh * 4 + r;
      ao[(b * 1024 + row) * 1024 + h * 64 + dt * 16 + lr] = f2bf(o[dt][r] / lsum[r]);
    }
}

// ---------------- launch ----------------
extern "C" void kernel_launch(void* const* d_in, const int* in_sizes, int n_in,
                              void* d_out, int out_size, void* d_ws, size_t ws_size,
                              hipStream_t stream) {
  const float* x      = (const float*)d_in[0];
  const float* w_qkv  = (const float*)d_in[1];
  const float* b_qkv  = (const float*)d_in[2];
  const float* w_proj = (const float*)d_in[3];
  const float* b_proj = (const float*)d_in[4];
  float* out = (float*)d_out;
  char* ws = (char*)d_ws;

  u16* X16   = (u16*)ws;                   //  8,388,608 B  [4096][1024] bf16 (reused as AO later)
  u16* Wqkv  = (u16*)(ws + 8388608);       //  6,291,456 B  [3072][1024] bf16
  u16* Wproj = (u16*)(ws + 14680064);      //  2,097,152 B  [1024][1024] bf16
  u16* Q     = (u16*)(ws + 16777216);      //  8,388,608 B  [64][1024][64]
  u16* K     = (u16*)(ws + 25165824);      //  8,388,608 B  [64][1024][64]
  u16* VT    = (u16*)(ws + 33554432);      //  8,388,608 B  [64][64][1024]
  u16* AO    = X16;                        // reuse x16 buffer for attention output

  k_cvt_x<<<dim3(2048), dim3(256), 0, stream>>>(x, X16);
  k_transpose_cvt<<<dim3(96, 32), dim3(32, 8), 0, stream>>>(w_qkv, Wqkv, 1024, 3072);
  k_transpose_cvt<<<dim3(32, 32), dim3(32, 8), 0, stream>>>(w_proj, Wproj, 1024, 1024);
  k_gemm<1><<<dim3(24, 32), dim3(256), 0, stream>>>(X16, Wqkv, b_qkv, Q, K, VT, (float*)0, 3072);
  k_attn<<<dim3(1024), dim3(256), 0, stream>>>(Q, K, VT, AO);
  k_gemm<0><<<dim3(8, 32), dim3(256), 0, stream>>>(AO, Wproj, b_proj, (u16*)0, (u16*)0, (u16*)0, out, 1024);
}

// Round 2
// 147.266 us; speedup vs baseline: 1.0124x; 1.0124x over previous
//
#include <hip/hip_runtime.h>

typedef unsigned short u16;
typedef unsigned int u32;
typedef __attribute__((ext_vector_type(8))) short bf16x8;
typedef __attribute__((ext_vector_type(4))) float f32x4;

#define LOG2E 1.4426950408889634f
#define QSCALE (0.125f * LOG2E)

__device__ __forceinline__ u16 f2bf(float f) {
  union { float f; u32 u; } x; x.f = f;
  u32 r = x.u + 0x7fffu + ((x.u >> 16) & 1u);   // RNE; inputs are finite
  return (u16)(r >> 16);
}

__device__ __forceinline__ void gload_lds16(const void* g, void* l) {
  __builtin_amdgcn_global_load_lds((const __attribute__((address_space(1))) u32*)g,
                                   (__attribute__((address_space(3))) u32*)l, 16, 0, 0);
}

// ---------------- prep: fp32 -> bf16 (x), 8 elems/thread ----------------
__global__ __launch_bounds__(256) void k_cvt_x(const float* __restrict__ in, u16* __restrict__ out) {
  int i = blockIdx.x * 256 + threadIdx.x;
  const float4* p = (const float4*)in;
  float4 a = p[i * 2], b = p[i * 2 + 1];
  uint4 o;
  o.x = (u32)f2bf(a.x) | ((u32)f2bf(a.y) << 16);
  o.y = (u32)f2bf(a.z) | ((u32)f2bf(a.w) << 16);
  o.z = (u32)f2bf(b.x) | ((u32)f2bf(b.y) << 16);
  o.w = (u32)f2bf(b.z) | ((u32)f2bf(b.w) << 16);
  ((uint4*)out)[i] = o;
}

// ---------------- prep: transpose + convert: src[R][Cc] f32 -> dst[Cc][R] bf16 ----------------
__global__ __launch_bounds__(256) void k_transpose_cvt(const float* __restrict__ src, u16* __restrict__ dst,
                                                       int R, int Cc) {
  __shared__ float tile[32][33];
  int c0 = blockIdx.x * 32, r0 = blockIdx.y * 32;
  int tx = threadIdx.x, ty = threadIdx.y;   // (32,8)
  #pragma unroll
  for (int j = 0; j < 4; ++j)
    tile[ty * 4 + j][tx] = src[(r0 + ty * 4 + j) * Cc + c0 + tx];
  __syncthreads();
  #pragma unroll
  for (int j = 0; j < 4; ++j) {
    int cl = ty * 4 + j;
    dst[(c0 + cl) * R + r0 + tx] = f2bf(tile[tx][cl]);
  }
}

// ---------------- 128x128 bf16 GEMM core (m97 structure), K=1024, BK=32 ----------------
// A  : [M][1024] bf16 row-major
// Bt : [N][1024] bf16 row-major (transposed weight: Bt[n][k])
// EPI 0: of[m][col] = acc + bias[col]  (fp32, N=ncols)
// EPI 1: qkv scatter: cols [0,1024)->q (scaled), [1024,2048)->k, [2048,3072)->vt (LDS transposed)
template <int EPI>
__global__ __launch_bounds__(256) void k_gemm(const u16* __restrict__ A, const u16* __restrict__ Bt,
                                              const float* __restrict__ bias,
                                              u16* __restrict__ oq, u16* __restrict__ ok,
                                              u16* __restrict__ ovt, float* __restrict__ of, int N) {
  __shared__ u16 lds[EPI ? 17408 : 8192];   // stage: A[128][32]+B[128][32]=8192; EPI1 transpose: 128*136
  const int tid = threadIdx.x;
  const int l = tid & 63, w = tid >> 6;
  const int wm = w >> 1, wn = w & 1;
  const int lr = l & 15, lh = l >> 4;
  const int bm = blockIdx.y, bn = blockIdx.x;
  u16* As = lds;
  u16* Bs = lds + 4096;
  f32x4 acc[4][4] = {};
  const int e = tid * 8;                    // staging element idx; row=e>>5, col=e&31
  const u16* gA = A + (bm * 128 + (e >> 5)) * 1024 + (e & 31);
  const u16* gB = Bt + (bn * 128 + (e >> 5)) * 1024 + (e & 31);

  for (int kk = 0; kk < 1024; kk += 32) {
    __syncthreads();
    gload_lds16(gA + kk,          As + e);
    gload_lds16(gA + kk + 65536,  As + e + 2048);   // +64 rows
    gload_lds16(gB + kk,          Bs + e);
    gload_lds16(gB + kk + 65536,  Bs + e + 2048);
    __syncthreads();
    bf16x8 af[4], bfr[4];
    #pragma unroll
    for (int mi = 0; mi < 4; ++mi)
      af[mi] = *(const bf16x8*)(As + (wm * 64 + mi * 16 + lr) * 32 + lh * 8);
    #pragma unroll
    for (int ni = 0; ni < 4; ++ni)
      bfr[ni] = *(const bf16x8*)(Bs + (wn * 64 + ni * 16 + lr) * 32 + lh * 8);
    #pragma unroll
    for (int mi = 0; mi < 4; ++mi)
      #pragma unroll
      for (int ni = 0; ni < 4; ++ni)
        acc[mi][ni] = __builtin_amdgcn_mfma_f32_16x16x32_bf16(af[mi], bfr[ni], acc[mi][ni], 0, 0, 0);
  }

  if (EPI == 0) {
    #pragma unroll
    for (int ni = 0; ni < 4; ++ni) {
      int col = bn * 128 + wn * 64 + ni * 16 + lr;
      float bb = bias[col];
      #pragma unroll
      for (int mi = 0; mi < 4; ++mi) {
        int row = bm * 128 + wm * 64 + mi * 16 + lh * 4;
        #pragma unroll
        for (int r = 0; r < 4; ++r)
          of[(row + r) * N + col] = acc[mi][ni][r] + bb;
      }
    }
  } else {
    int s = bn >> 3;   // 1024-aligned thirds (bn in [0,24))
    if (s < 2) {
      u16* dst = (s == 0) ? oq : ok;
      const float sc = (s == 0) ? QSCALE : 1.0f;
      #pragma unroll
      for (int ni = 0; ni < 4; ++ni) {
        int c = bn * 128 + wn * 64 + ni * 16 + lr;
        float bb = bias[c];
        int cc = c & 1023, h = cc >> 6, d = cc & 63;
        #pragma unroll
        for (int mi = 0; mi < 4; ++mi) {
          int rowb = bm * 128 + wm * 64 + mi * 16 + lh * 4;
          #pragma unroll
          for (int r = 0; r < 4; ++r) {
            int m = rowb + r, b = m >> 10, n = m & 1023;
            dst[((b * 16 + h) * 1024 + n) * 64 + d] = f2bf((acc[mi][ni][r] + bb) * sc);
          }
        }
      }
    } else {
      // v: transpose 128x128 tile via LDS (stride 136), write [bh][d][n] coalesced
      __syncthreads();
      #pragma unroll
      for (int ni = 0; ni < 4; ++ni) {
        int cl = wn * 64 + ni * 16 + lr;
        float bb = bias[bn * 128 + cl];
        #pragma unroll
        for (int mi = 0; mi < 4; ++mi) {
          int rl = wm * 64 + mi * 16 + lh * 4;
          u32 p0 = (u32)f2bf(acc[mi][ni][0] + bb) | ((u32)f2bf(acc[mi][ni][1] + bb) << 16);
          u32 p1 = (u32)f2bf(acc[mi][ni][2] + bb) | ((u32)f2bf(acc[mi][ni][3] + bb) << 16);
          uint2 pk; pk.x = p0; pk.y = p1;
          *(uint2*)(lds + cl * 136 + rl) = pk;
        }
      }
      __syncthreads();
      int cl = tid >> 1, half = tid & 1;
      int c = bn * 128 + cl, cc = c & 1023, h = cc >> 6, d = cc & 63;
      int b = (bm * 128) >> 10, n0 = (bm * 128) & 1023;
      const u16* srow = lds + cl * 136 + half * 64;
      u16* drow = ovt + ((b * 16 + h) * 64 + d) * 1024 + n0 + half * 64;
      #pragma unroll
      for (int j = 0; j < 8; ++j)
        *(uint4*)(drow + j * 8) = *(const uint4*)(srow + j * 8);
    }
  }
}

// ---------------- flash attention: 1 block = (bh, 64-row q-block), 4 waves x 16 rows ----------------
// Double-buffered K/V prefetch with counted vmcnt (T3/T4 minimal 2-phase).
// q,k: [bh][n][64] bf16 (q pre-scaled by 0.125*log2e); vt: [bh][64][n] bf16; ao: [b][n][h*64+d] bf16
__global__ __launch_bounds__(256) void k_attn(const u16* __restrict__ q, const u16* __restrict__ k,
                                              const u16* __restrict__ vt, u16* __restrict__ ao) {
  __shared__ u16 Ks[2][4096], Vs[2][4096], Ps[4096];
  const int tid = threadIdx.x, l = tid & 63, w = tid >> 6;
  const int lr = l & 15, lh = l >> 4;
  const int bh = blockIdx.x >> 4, qb = blockIdx.x & 15;

  const u16* qg = q + bh * 65536 + (qb * 64 + w * 16) * 64;
  bf16x8 qa[2];
  qa[0] = *(const bf16x8*)(qg + lr * 64 + lh * 8);
  qa[1] = *(const bf16x8*)(qg + lr * 64 + lh * 8 + 32);

  float mr[4], lsum[4];
  f32x4 o[4] = {};
  #pragma unroll
  for (int r = 0; r < 4; ++r) { mr[r] = -1e30f; lsum[r] = 0.f; }

  const u16* kg = k + bh * 65536;
  const u16* vg = vt + bh * 65536;

  // per-thread staging geometry: 2 chunks each for K and V (4 gload_lds per stage)
  const int ch0 = tid, ch1 = 256 + tid;
  const int r0_ = ch0 >> 3, s0_ = (ch0 & 7) ^ (r0_ & 7);   // pre-swizzled global source
  const int r1_ = ch1 >> 3, s1_ = (ch1 & 7) ^ (r1_ & 7);

  #define STAGE(t, buf)                                                        \
    do {                                                                       \
      gload_lds16(kg + (t) * 4096 + r0_ * 64 + s0_ * 8, Ks[buf] + ch0 * 8);    \
      gload_lds16(vg + r0_ * 1024 + (t) * 64 + s0_ * 8, Vs[buf] + ch0 * 8);    \
      gload_lds16(kg + (t) * 4096 + r1_ * 64 + s1_ * 8, Ks[buf] + ch1 * 8);    \
      gload_lds16(vg + r1_ * 1024 + (t) * 64 + s1_ * 8, Vs[buf] + ch1 * 8);    \
    } while (0)

  STAGE(0, 0);

  for (int t = 0; t < 16; ++t) {
    const int cur = t & 1;
    if (t < 15) {
      STAGE(t + 1, cur ^ 1);
      asm volatile("s_waitcnt vmcnt(4)" ::: "memory");   // tile-t loads (oldest 4) done
    } else {
      asm volatile("s_waitcnt vmcnt(0)" ::: "memory");
    }
    __builtin_amdgcn_s_barrier();            // all waves' tile-t data in LDS
    __builtin_amdgcn_sched_barrier(0);       // don't hoist ds_reads above the barrier

    // S = q @ k^T  (scores already in log2 domain via QSCALE)
    f32x4 sv[4] = {};
    #pragma unroll
    for (int ni = 0; ni < 4; ++ni) {
      int row = ni * 16 + lr;
      #pragma unroll
      for (int kt = 0; kt < 2; ++kt) {
        int off = (row * 128 + lh * 16 + kt * 64) ^ ((row & 7) << 4);
        bf16x8 kf = *(const bf16x8*)((const char*)Ks[cur] + off);
        sv[ni] = __builtin_amdgcn_mfma_f32_16x16x32_bf16(qa[kt], kf, sv[ni], 0, 0, 0);
      }
    }

    // online softmax (rows live on 16 lanes of same lh group)
    float al[4];
    #pragma unroll
    for (int r = 0; r < 4; ++r) {
      float m0 = fmaxf(fmaxf(sv[0][r], sv[1][r]), fmaxf(sv[2][r], sv[3][r]));
      m0 = fmaxf(m0, __shfl_xor(m0, 1, 16));
      m0 = fmaxf(m0, __shfl_xor(m0, 2, 16));
      m0 = fmaxf(m0, __shfl_xor(m0, 4, 16));
      m0 = fmaxf(m0, __shfl_xor(m0, 8, 16));
      float nm = fmaxf(mr[r], m0);
      al[r] = __builtin_amdgcn_exp2f(mr[r] - nm);
      mr[r] = nm;
    }
    #pragma unroll
    for (int ni = 0; ni < 4; ++ni)
      #pragma unroll
      for (int r = 0; r < 4; ++r)
        sv[ni][r] = __builtin_amdgcn_exp2f(sv[ni][r] - mr[r]);
    #pragma unroll
    for (int r = 0; r < 4; ++r) {
      float s0 = (sv[0][r] + sv[1][r]) + (sv[2][r] + sv[3][r]);
      s0 += __shfl_xor(s0, 1, 16);
      s0 += __shfl_xor(s0, 2, 16);
      s0 += __shfl_xor(s0, 4, 16);
      s0 += __shfl_xor(s0, 8, 16);
      lsum[r] = lsum[r] * al[r] + s0;
    }
    #pragma unroll
    for (int dt = 0; dt < 4; ++dt)
      #pragma unroll
      for (int r = 0; r < 4; ++r)
        o[dt][r] *= al[r];

    // P -> LDS (wave-private, rotation swizzle: conflict-lite writes, aligned 16B reads)
    #pragma unroll
    for (int ni = 0; ni < 4; ++ni) {
      int col = ni * 16 + lr;
      #pragma unroll
      for (int r = 0; r < 4; ++r) {
        int row = lh * 4 + r;
        int off = row * 128 + ((col * 2 + row * 16) & 127);
        *(u16*)((char*)Ps + w * 2048 + off) = f2bf(sv[ni][r]);
      }
    }
    bf16x8 pa[2];
    #pragma unroll
    for (int kt = 0; kt < 2; ++kt) {
      int off = lr * 128 + (((lh * 8 + kt * 32) * 2 + lr * 16) & 127);
      pa[kt] = *(const bf16x8*)((const char*)Ps + w * 2048 + off);
    }
    // O += P @ V
    #pragma unroll
    for (int dt = 0; dt < 4; ++dt) {
      int row = dt * 16 + lr;
      #pragma unroll
      for (int kt = 0; kt < 2; ++kt) {
        int off = (row * 128 + lh * 16 + kt * 64) ^ ((row & 7) << 4);
        bf16x8 vf = *(const bf16x8*)((const char*)Vs[cur] + off);
        o[dt] = __builtin_amdgcn_mfma_f32_16x16x32_bf16(pa[kt], vf, o[dt], 0, 0, 0);
      }
    }

    __builtin_amdgcn_s_barrier();            // all reads of buf[cur] done before it is re-staged
  }
  #undef STAGE

  const int b = bh >> 4, h = bh & 15;
  #pragma unroll
  for (int dt = 0; dt < 4; ++dt)
    #pragma unroll
    for (int r = 0; r < 4; ++r) {
      int row = qb * 64 + w * 16 + lh * 4 + r;
      ao[(b * 1024 + row) * 1024 + h * 64 + dt * 16 + lr] = f2bf(o[dt][r] / lsum[r]);
    }
}

// ---------------- launch ----------------
extern "C" void kernel_launch(void* const* d_in, const int* in_sizes, int n_in,
                              void* d_out, int out_size, void* d_ws, size_t ws_size,
                              hipStream_t stream) {
  const float* x      = (const float*)d_in[0];
  const float* w_qkv  = (const float*)d_in[1];
  const float* b_qkv  = (const float*)d_in[2];
  const float* w_proj = (const float*)d_in[3];
  const float* b_proj = (const float*)d_in[4];
  float* out = (float*)d_out;
  char* ws = (char*)d_ws;

  u16* X16   = (u16*)ws;                   //  8,388,608 B  [4096][1024] bf16 (reused as AO later)
  u16* Wqkv  = (u16*)(ws + 8388608);       //  6,291,456 B  [3072][1024] bf16
  u16* Wproj = (u16*)(ws + 14680064);      //  2,097,152 B  [1024][1024] bf16
  u16* Q     = (u16*)(ws + 16777216);      //  8,388,608 B  [64][1024][64]
  u16* K     = (u16*)(ws + 25165824);      //  8,388,608 B  [64][1024][64]
  u16* VT    = (u16*)(ws + 33554432);      //  8,388,608 B  [64][64][1024]
  u16* AO    = X16;                        // reuse x16 buffer for attention output

  k_cvt_x<<<dim3(2048), dim3(256), 0, stream>>>(x, X16);
  k_transpose_cvt<<<dim3(96, 32), dim3(32, 8), 0, stream>>>(w_qkv, Wqkv, 1024, 3072);
  k_transpose_cvt<<<dim3(32, 32), dim3(32, 8), 0, stream>>>(w_proj, Wproj, 1024, 1024);
  k_gemm<1><<<dim3(24, 32), dim3(256), 0, stream>>>(X16, Wqkv, b_qkv, Q, K, VT, (float*)0, 3072);
  k_attn<<<dim3(1024), dim3(256), 0, stream>>>(Q, K, VT, AO);
  k_gemm<0><<<dim3(8, 32), dim3(256), 0, stream>>>(AO, Wproj, b_proj, (u16*)0, (u16*)0, (u16*)0, out, 1024);
}

// Round 3
// 122.433 us; speedup vs baseline: 1.2178x; 1.2028x over previous
//
#include <hip/hip_runtime.h>

typedef unsigned short u16;
typedef unsigned int u32;
typedef __attribute__((ext_vector_type(8))) short bf16x8;
typedef __attribute__((ext_vector_type(4))) float f32x4;
typedef __attribute__((ext_vector_type(16))) float f32x16;

#define LOG2E 1.4426950408889634f
#define QSCALE (0.125f * LOG2E)

__device__ __forceinline__ u16 f2bf(float f) {
  union { float f; u32 u; } x; x.f = f;
  u32 r = x.u + 0x7fffu + ((x.u >> 16) & 1u);   // RNE; inputs are finite
  return (u16)(r >> 16);
}

__device__ __forceinline__ u32 cvtpk(float a, float b) {
  u32 r;
  asm("v_cvt_pk_bf16_f32 %0, %1, %2" : "=v"(r) : "v"(a), "v"(b));
  return r;
}

__device__ __forceinline__ bf16x8 mkfrag(u32 a, u32 b, u32 c, u32 d) {
  union { u32 w[4]; bf16x8 v; } u;
  u.w[0] = a; u.w[1] = b; u.w[2] = c; u.w[3] = d;
  return u.v;
}

__device__ __forceinline__ void gload_lds16(const void* g, void* l) {
  __builtin_amdgcn_global_load_lds((const __attribute__((address_space(1))) u32*)g,
                                   (__attribute__((address_space(3))) u32*)l, 16, 0, 0);
}

// ---------------- prep: fp32 -> bf16 (x), 8 elems/thread ----------------
__global__ __launch_bounds__(256) void k_cvt_x(const float* __restrict__ in, u16* __restrict__ out) {
  int i = blockIdx.x * 256 + threadIdx.x;
  const float4* p = (const float4*)in;
  float4 a = p[i * 2], b = p[i * 2 + 1];
  uint4 o;
  o.x = (u32)f2bf(a.x) | ((u32)f2bf(a.y) << 16);
  o.y = (u32)f2bf(a.z) | ((u32)f2bf(a.w) << 16);
  o.z = (u32)f2bf(b.x) | ((u32)f2bf(b.y) << 16);
  o.w = (u32)f2bf(b.z) | ((u32)f2bf(b.w) << 16);
  ((uint4*)out)[i] = o;
}

// ---------------- prep: transpose + convert: src[R][Cc] f32 -> dst[Cc][R] bf16 ----------------
__global__ __launch_bounds__(256) void k_transpose_cvt(const float* __restrict__ src, u16* __restrict__ dst,
                                                       int R, int Cc) {
  __shared__ float tile[32][33];
  int c0 = blockIdx.x * 32, r0 = blockIdx.y * 32;
  int tx = threadIdx.x, ty = threadIdx.y;   // (32,8)
  #pragma unroll
  for (int j = 0; j < 4; ++j)
    tile[ty * 4 + j][tx] = src[(r0 + ty * 4 + j) * Cc + c0 + tx];
  __syncthreads();
  #pragma unroll
  for (int j = 0; j < 4; ++j) {
    int cl = ty * 4 + j;
    dst[(c0 + cl) * R + r0 + tx] = f2bf(tile[tx][cl]);
  }
}

// ---------------- 128x128 bf16 GEMM core (m97 structure), K=1024, BK=32 ----------------
template <int EPI>
__global__ __launch_bounds__(256) void k_gemm(const u16* __restrict__ A, const u16* __restrict__ Bt,
                                              const float* __restrict__ bias,
                                              u16* __restrict__ oq, u16* __restrict__ ok,
                                              u16* __restrict__ ovt, float* __restrict__ of, int N) {
  __shared__ u16 lds[EPI ? 17408 : 8192];
  const int tid = threadIdx.x;
  const int l = tid & 63, w = tid >> 6;
  const int wm = w >> 1, wn = w & 1;
  const int lr = l & 15, lh = l >> 4;
  const int bm = blockIdx.y, bn = blockIdx.x;
  u16* As = lds;
  u16* Bs = lds + 4096;
  f32x4 acc[4][4] = {};
  const int e = tid * 8;
  const u16* gA = A + (bm * 128 + (e >> 5)) * 1024 + (e & 31);
  const u16* gB = Bt + (bn * 128 + (e >> 5)) * 1024 + (e & 31);

  for (int kk = 0; kk < 1024; kk += 32) {
    __syncthreads();
    gload_lds16(gA + kk,          As + e);
    gload_lds16(gA + kk + 65536,  As + e + 2048);
    gload_lds16(gB + kk,          Bs + e);
    gload_lds16(gB + kk + 65536,  Bs + e + 2048);
    __syncthreads();
    bf16x8 af[4], bfr[4];
    #pragma unroll
    for (int mi = 0; mi < 4; ++mi)
      af[mi] = *(const bf16x8*)(As + (wm * 64 + mi * 16 + lr) * 32 + lh * 8);
    #pragma unroll
    for (int ni = 0; ni < 4; ++ni)
      bfr[ni] = *(const bf16x8*)(Bs + (wn * 64 + ni * 16 + lr) * 32 + lh * 8);
    #pragma unroll
    for (int mi = 0; mi < 4; ++mi)
      #pragma unroll
      for (int ni = 0; ni < 4; ++ni)
        acc[mi][ni] = __builtin_amdgcn_mfma_f32_16x16x32_bf16(af[mi], bfr[ni], acc[mi][ni], 0, 0, 0);
  }

  if (EPI == 0) {
    #pragma unroll
    for (int ni = 0; ni < 4; ++ni) {
      int col = bn * 128 + wn * 64 + ni * 16 + lr;
      float bb = bias[col];
      #pragma unroll
      for (int mi = 0; mi < 4; ++mi) {
        int row = bm * 128 + wm * 64 + mi * 16 + lh * 4;
        #pragma unroll
        for (int r = 0; r < 4; ++r)
          of[(row + r) * N + col] = acc[mi][ni][r] + bb;
      }
    }
  } else {
    int s = bn >> 3;
    if (s < 2) {
      u16* dst = (s == 0) ? oq : ok;
      const float sc = (s == 0) ? QSCALE : 1.0f;
      #pragma unroll
      for (int ni = 0; ni < 4; ++ni) {
        int c = bn * 128 + wn * 64 + ni * 16 + lr;
        float bb = bias[c];
        int cc = c & 1023, h = cc >> 6, d = cc & 63;
        #pragma unroll
        for (int mi = 0; mi < 4; ++mi) {
          int rowb = bm * 128 + wm * 64 + mi * 16 + lh * 4;
          #pragma unroll
          for (int r = 0; r < 4; ++r) {
            int m = rowb + r, b = m >> 10, n = m & 1023;
            dst[((b * 16 + h) * 1024 + n) * 64 + d] = f2bf((acc[mi][ni][r] + bb) * sc);
          }
        }
      }
    } else {
      __syncthreads();
      #pragma unroll
      for (int ni = 0; ni < 4; ++ni) {
        int cl = wn * 64 + ni * 16 + lr;
        float bb = bias[bn * 128 + cl];
        #pragma unroll
        for (int mi = 0; mi < 4; ++mi) {
          int rl = wm * 64 + mi * 16 + lh * 4;
          u32 p0 = (u32)f2bf(acc[mi][ni][0] + bb) | ((u32)f2bf(acc[mi][ni][1] + bb) << 16);
          u32 p1 = (u32)f2bf(acc[mi][ni][2] + bb) | ((u32)f2bf(acc[mi][ni][3] + bb) << 16);
          uint2 pk; pk.x = p0; pk.y = p1;
          *(uint2*)(lds + cl * 136 + rl) = pk;
        }
      }
      __syncthreads();
      int cl = tid >> 1, half = tid & 1;
      int c = bn * 128 + cl, cc = c & 1023, h = cc >> 6, d = cc & 63;
      int b = (bm * 128) >> 10, n0 = (bm * 128) & 1023;
      const u16* srow = lds + cl * 136 + half * 64;
      u16* drow = ovt + ((b * 16 + h) * 64 + d) * 1024 + n0 + half * 64;
      #pragma unroll
      for (int j = 0; j < 8; ++j)
        *(uint4*)(drow + j * 8) = *(const uint4*)(srow + j * 8);
    }
  }
}

// ---------------- flash attention, swapped-QK^T 32x32 in-register softmax ----------------
// 1 block = (bh, 128-row q-block), 4 waves x 32 q-rows, KVBLK=64, double-buffered K/V.
// q,k: [bh][n][64] bf16 (q pre-scaled by 0.125*log2e); vt: [bh][64][n] bf16; ao: [b][n][h*64+d] bf16
__global__ __launch_bounds__(256) void k_attn(const u16* __restrict__ q, const u16* __restrict__ k,
                                              const u16* __restrict__ vt, u16* __restrict__ ao) {
  __shared__ u16 Ks[2][4096], Vs[2][4096];   // [64 rows][64] bf16, XOR-swizzled, 32 KB total
  const int tid = threadIdx.x, l = tid & 63, w = tid >> 6;
  const int lq = l & 31;          // this lane's q-row within the warp tile (and d-col of O)
  const int hi = l >> 5;          // half-wave
  // XCD-aware decode: all 8 q-blocks of one bh land on the same XCD (i%8 const)
  const int i = blockIdx.x;
  const int bh = (i & 7) * 8 + ((i >> 3) & 7);
  const int qb = i >> 6;          // 0..7

  const int qrow = qb * 128 + w * 32 + lq;
  const u16* qg = q + bh * 65536 + qrow * 64;
  bf16x8 qf[4];
  #pragma unroll
  for (int ks = 0; ks < 4; ++ks)
    qf[ks] = *(const bf16x8*)(qg + ks * 16 + hi * 8);   // Q[qrow][ks*16 + hi*8 + j]

  float mr = -1e30f, lsum = 0.f;
  f32x16 o0 = {}, o1 = {};        // O[q=crow(r,hi)][d = dt*32 + lq]

  const u16* kg = k + bh * 65536;
  const u16* vg = vt + bh * 65536;

  // staging: K tile (64 keys x 64d) + V tile (64d x 64n), 2 chunks each per thread
  const int ch0 = tid, ch1 = 256 + tid;
  const int r0_ = ch0 >> 3, s0_ = (ch0 & 7) ^ (r0_ & 7);
  const int r1_ = ch1 >> 3, s1_ = (ch1 & 7) ^ (r1_ & 7);

  #define STAGE(t, buf)                                                        \
    do {                                                                       \
      gload_lds16(kg + (t) * 4096 + r0_ * 64 + s0_ * 8, Ks[buf] + ch0 * 8);    \
      gload_lds16(vg + r0_ * 1024 + (t) * 64 + s0_ * 8, Vs[buf] + ch0 * 8);    \
      gload_lds16(kg + (t) * 4096 + r1_ * 64 + s1_ * 8, Ks[buf] + ch1 * 8);    \
      gload_lds16(vg + r1_ * 1024 + (t) * 64 + s1_ * 8, Vs[buf] + ch1 * 8);    \
    } while (0)

  STAGE(0, 0);

  const int swz = (lq & 7) << 4;

  for (int t = 0; t < 16; ++t) {
    const int cur = t & 1;
    if (t < 15) {
      STAGE(t + 1, cur ^ 1);
      asm volatile("s_waitcnt vmcnt(4)" ::: "memory");
    } else {
      asm volatile("s_waitcnt vmcnt(0)" ::: "memory");
    }
    __builtin_amdgcn_s_barrier();
    __builtin_amdgcn_sched_barrier(0);

    // ---- S^T = K * Q^T : lane holds S[q=lq][key = st*32 + crow(r,hi)] ----
    f32x16 sA = {}, sB = {};
    __builtin_amdgcn_s_setprio(1);
    #pragma unroll
    for (int ks = 0; ks < 4; ++ks) {
      bf16x8 kf0 = *(const bf16x8*)((const char*)Ks[cur] + (((lq) * 128 + ks * 32 + hi * 16) ^ swz));
      bf16x8 kf1 = *(const bf16x8*)((const char*)Ks[cur] + (((32 + lq) * 128 + ks * 32 + hi * 16) ^ swz));
      sA = __builtin_amdgcn_mfma_f32_32x32x16_bf16(kf0, qf[ks], sA, 0, 0, 0);
      sB = __builtin_amdgcn_mfma_f32_32x32x16_bf16(kf1, qf[ks], sB, 0, 0, 0);
    }
    __builtin_amdgcn_s_setprio(0);

    // ---- online softmax, fully in-register (scores in log2 domain) ----
    float pmax = sA[0];
    #pragma unroll
    for (int r = 1; r < 16; ++r) pmax = fmaxf(pmax, sA[r]);
    #pragma unroll
    for (int r = 0; r < 16; ++r) pmax = fmaxf(pmax, sB[r]);
    pmax = fmaxf(pmax, __shfl_xor(pmax, 32));

    if (!__all(pmax - mr <= 8.0f)) {        // defer-max (T13): rescale rarely
      float nm = fmaxf(mr, pmax);
      float al = __builtin_amdgcn_exp2f(mr - nm);
      mr = nm;
      lsum *= al;
      #pragma unroll
      for (int r = 0; r < 16; ++r) {
        int row = (r & 3) + 8 * (r >> 2) + 4 * hi;
        float f = __shfl(al, row, 64);
        o0[r] *= f; o1[r] *= f;
      }
    }

    float ls = 0.f;
    #pragma unroll
    for (int r = 0; r < 16; ++r) { float e = __builtin_amdgcn_exp2f(sA[r] - mr); sA[r] = e; ls += e; }
    #pragma unroll
    for (int r = 0; r < 16; ++r) { float e = __builtin_amdgcn_exp2f(sB[r] - mr); sB[r] = e; ls += e; }
    lsum += ls;

    // ---- pack P to bf16 + lo/hi half exchange -> A-fragments pa[4] ----
    u32 wa[8], wb[8];
    #pragma unroll
    for (int j = 0; j < 8; ++j) {
      wa[j] = cvtpk(sA[2 * j], sA[2 * j + 1]);
      wb[j] = cvtpk(sB[2 * j], sB[2 * j + 1]);
    }
    u32 xa0 = __shfl_xor((int)wa[0], 32), xa1 = __shfl_xor((int)wa[1], 32);
    u32 xa2 = __shfl_xor((int)wa[2], 32), xa3 = __shfl_xor((int)wa[3], 32);
    u32 xa4 = __shfl_xor((int)wa[4], 32), xa5 = __shfl_xor((int)wa[5], 32);
    u32 xa6 = __shfl_xor((int)wa[6], 32), xa7 = __shfl_xor((int)wa[7], 32);
    u32 xb0 = __shfl_xor((int)wb[0], 32), xb1 = __shfl_xor((int)wb[1], 32);
    u32 xb2 = __shfl_xor((int)wb[2], 32), xb3 = __shfl_xor((int)wb[3], 32);
    u32 xb4 = __shfl_xor((int)wb[4], 32), xb5 = __shfl_xor((int)wb[5], 32);
    u32 xb6 = __shfl_xor((int)wb[6], 32), xb7 = __shfl_xor((int)wb[7], 32);
    // frag word layout per half: lo lane gets k 0..7, hi lane k 8..15 of each 16-key slot
    bf16x8 pa0 = mkfrag(hi ? xa2 : wa[0], hi ? xa3 : wa[1], hi ? wa[2] : xa0, hi ? wa[3] : xa1);
    bf16x8 pa1 = mkfrag(hi ? xa6 : wa[4], hi ? xa7 : wa[5], hi ? wa[6] : xa4, hi ? wa[7] : xa5);
    bf16x8 pa2 = mkfrag(hi ? xb2 : wb[0], hi ? xb3 : wb[1], hi ? wb[2] : xb0, hi ? wb[3] : xb1);
    bf16x8 pa3 = mkfrag(hi ? xb6 : wb[4], hi ? xb7 : wb[5], hi ? wb[6] : xb4, hi ? wb[7] : xb5);

    // ---- O += P * V ----
    __builtin_amdgcn_s_setprio(1);
    #pragma unroll
    for (int ks = 0; ks < 4; ++ks) {
      bf16x8 pf = (ks == 0) ? pa0 : (ks == 1) ? pa1 : (ks == 2) ? pa2 : pa3;
      bf16x8 vf0 = *(const bf16x8*)((const char*)Vs[cur] + (((lq) * 128 + ks * 32 + hi * 16) ^ swz));
      bf16x8 vf1 = *(const bf16x8*)((const char*)Vs[cur] + (((32 + lq) * 128 + ks * 32 + hi * 16) ^ swz));
      o0 = __builtin_amdgcn_mfma_f32_32x32x16_bf16(pf, vf0, o0, 0, 0, 0);
      o1 = __builtin_amdgcn_mfma_f32_32x32x16_bf16(pf, vf1, o1, 0, 0, 0);
    }
    __builtin_amdgcn_s_setprio(0);

    __builtin_amdgcn_s_barrier();
  }
  #undef STAGE

  // ---- epilogue: divide by row-sum, coalesced bf16 stores ----
  lsum += __shfl_xor(lsum, 32);
  const int b = bh >> 4, h = bh & 15;
  u16* aob = ao + (u32)(b * 1024 + qb * 128 + w * 32) * 1024 + h * 64;
  #pragma unroll
  for (int r = 0; r < 16; ++r) {
    int row = (r & 3) + 8 * (r >> 2) + 4 * hi;
    float inv = 1.0f / __shfl(lsum, row, 64);
    aob[row * 1024 + lq]      = f2bf(o0[r] * inv);
    aob[row * 1024 + 32 + lq] = f2bf(o1[r] * inv);
  }
}

// ---------------- launch ----------------
extern "C" void kernel_launch(void* const* d_in, const int* in_sizes, int n_in,
                              void* d_out, int out_size, void* d_ws, size_t ws_size,
                              hipStream_t stream) {
  const float* x      = (const float*)d_in[0];
  const float* w_qkv  = (const float*)d_in[1];
  const float* b_qkv  = (const float*)d_in[2];
  const float* w_proj = (const float*)d_in[3];
  const float* b_proj = (const float*)d_in[4];
  float* out = (float*)d_out;
  char* ws = (char*)d_ws;

  u16* X16   = (u16*)ws;
  u16* Wqkv  = (u16*)(ws + 8388608);
  u16* Wproj = (u16*)(ws + 14680064);
  u16* Q     = (u16*)(ws + 16777216);
  u16* K     = (u16*)(ws + 25165824);
  u16* VT    = (u16*)(ws + 33554432);
  u16* AO    = X16;

  k_cvt_x<<<dim3(2048), dim3(256), 0, stream>>>(x, X16);
  k_transpose_cvt<<<dim3(96, 32), dim3(32, 8), 0, stream>>>(w_qkv, Wqkv, 1024, 3072);
  k_transpose_cvt<<<dim3(32, 32), dim3(32, 8), 0, stream>>>(w_proj, Wproj, 1024, 1024);
  k_gemm<1><<<dim3(24, 32), dim3(256), 0, stream>>>(X16, Wqkv, b_qkv, Q, K, VT, (float*)0, 3072);
  k_attn<<<dim3(512), dim3(256), 0, stream>>>(Q, K, VT, AO);
  k_gemm<0><<<dim3(8, 32), dim3(256), 0, stream>>>(AO, Wproj, b_proj, (u16*)0, (u16*)0, (u16*)0, out, 1024);
}

// Round 5
// 114.325 us; speedup vs baseline: 1.3041x; 1.0709x over previous
//
#include <hip/hip_runtime.h>

typedef unsigned short u16;
typedef unsigned int u32;
typedef __attribute__((ext_vector_type(8))) short bf16x8;
typedef __attribute__((ext_vector_type(4))) float f32x4;
typedef __attribute__((ext_vector_type(16))) float f32x16;

#define LOG2E 1.4426950408889634f
#define QSCALE (0.125f * LOG2E)

__device__ __forceinline__ u16 f2bf(float f) {
  union { float f; u32 u; } x; x.f = f;
  u32 r = x.u + 0x7fffu + ((x.u >> 16) & 1u);   // RNE; inputs are finite
  return (u16)(r >> 16);
}

__device__ __forceinline__ u32 cvtpk(float a, float b) {
  u32 r;
  asm("v_cvt_pk_bf16_f32 %0, %1, %2" : "=v"(r) : "v"(a), "v"(b));
  return r;
}

__device__ __forceinline__ bf16x8 mkfrag(u32 a, u32 b, u32 c, u32 d) {
  union { u32 w[4]; bf16x8 v; } u;
  u.w[0] = a; u.w[1] = b; u.w[2] = c; u.w[3] = d;
  return u.v;
}

__device__ __forceinline__ void gload_lds16(const void* g, void* l) {
  __builtin_amdgcn_global_load_lds((const __attribute__((address_space(1))) u32*)g,
                                   (__attribute__((address_space(3))) u32*)l, 16, 0, 0);
}

// ---------------- prep: fp32 -> bf16 (x), 8 elems/thread ----------------
__global__ __launch_bounds__(256) void k_cvt_x(const float* __restrict__ in, u16* __restrict__ out) {
  int i = blockIdx.x * 256 + threadIdx.x;
  const float4* p = (const float4*)in;
  float4 a = p[i * 2], b = p[i * 2 + 1];
  uint4 o;
  o.x = (u32)f2bf(a.x) | ((u32)f2bf(a.y) << 16);
  o.y = (u32)f2bf(a.z) | ((u32)f2bf(a.w) << 16);
  o.z = (u32)f2bf(b.x) | ((u32)f2bf(b.y) << 16);
  o.w = (u32)f2bf(b.z) | ((u32)f2bf(b.w) << 16);
  ((uint4*)out)[i] = o;
}

// ---------------- prep: transpose + convert: src[R][Cc] f32 -> dst[Cc][R] bf16 ----------------
__global__ __launch_bounds__(256) void k_transpose_cvt(const float* __restrict__ src, u16* __restrict__ dst,
                                                       int R, int Cc) {
  __shared__ float tile[32][33];
  int c0 = blockIdx.x * 32, r0 = blockIdx.y * 32;
  int tx = threadIdx.x, ty = threadIdx.y;   // (32,8)
  #pragma unroll
  for (int j = 0; j < 4; ++j)
    tile[ty * 4 + j][tx] = src[(r0 + ty * 4 + j) * Cc + c0 + tx];
  __syncthreads();
  #pragma unroll
  for (int j = 0; j < 4; ++j) {
    int cl = ty * 4 + j;
    dst[(c0 + cl) * R + r0 + tx] = f2bf(tile[tx][cl]);
  }
}

// ---------------- 128x128 bf16 GEMM, K=1024, BK=32, 2-phase dbuf + counted vmcnt ----------------
// A  : [M][1024] bf16 row-major;  Bt : [N][1024] bf16 row-major (Bt[n][k])
// EPI 0: of[m][col] = acc + bias[col]  (fp32, N=NBN*128)
// EPI 1: qkv: cols [0,1024)->q (scaled, [bh][n][64]), [1024,2048)->k, [2048,3072)->vt ([bh][d][n])
template <int EPI, int NBN>
__global__ __launch_bounds__(256) void k_gemm(const u16* __restrict__ A, const u16* __restrict__ Bt,
                                              const float* __restrict__ bias,
                                              u16* __restrict__ oq, u16* __restrict__ ok,
                                              u16* __restrict__ ovt, float* __restrict__ of) {
  __shared__ u16 lds[EPI ? 17408 : 16384];   // dbuf staging 16384 u16; EPI1 epilogue reuses as [128][136]
  const int tid = threadIdx.x;
  const int l = tid & 63, w = tid >> 6;
  const int wm = w >> 1, wn = w & 1;
  const int lr = l & 15, lh = l >> 4;
  // bijective XCD chunk swizzle (gridDim.x % 8 == 0)
  const int cpx = gridDim.x >> 3;
  const int wg = (blockIdx.x & 7) * cpx + (blockIdx.x >> 3);
  const int bn = wg % NBN, bm = wg / NBN;

  // buffers: A half at lds + b*8192, B half at lds + 4096 + b*8192 (indexed by offset, no ptr tables)
  f32x4 acc[4][4] = {};
  const int e = tid * 8;                    // staging element idx; row=e>>5, col=e&31
  const u16* gA = A + (bm * 128 + (e >> 5)) * 1024 + (e & 31);
  const u16* gB = Bt + (bn * 128 + (e >> 5)) * 1024 + (e & 31);

  #define GSTAGE(kk, b)                                              \
    do {                                                             \
      gload_lds16(gA + (kk),         lds + (b) * 8192 + e);          \
      gload_lds16(gA + (kk) + 65536, lds + (b) * 8192 + e + 2048);   \
      gload_lds16(gB + (kk),         lds + (b) * 8192 + 4096 + e);   \
      gload_lds16(gB + (kk) + 65536, lds + (b) * 8192 + 4096 + e + 2048); \
    } while (0)

  GSTAGE(0, 0);

  for (int it = 0; it < 32; ++it) {
    const int cur = it & 1;
    if (it < 31) {
      GSTAGE((it + 1) * 32, cur ^ 1);
      asm volatile("s_waitcnt vmcnt(4)" ::: "memory");   // this tile's 4 loads (oldest) done
    } else {
      asm volatile("s_waitcnt vmcnt(0)" ::: "memory");
    }
    __builtin_amdgcn_s_barrier();
    __builtin_amdgcn_sched_barrier(0);

    const u16* Asc = lds + cur * 8192;
    const u16* Bsc = lds + cur * 8192 + 4096;
    bf16x8 af[4], bfr[4];
    #pragma unroll
    for (int mi = 0; mi < 4; ++mi)
      af[mi] = *(const bf16x8*)(Asc + (wm * 64 + mi * 16 + lr) * 32 + lh * 8);
    #pragma unroll
    for (int ni = 0; ni < 4; ++ni)
      bfr[ni] = *(const bf16x8*)(Bsc + (wn * 64 + ni * 16 + lr) * 32 + lh * 8);
    #pragma unroll
    for (int mi = 0; mi < 4; ++mi)
      #pragma unroll
      for (int ni = 0; ni < 4; ++ni)
        acc[mi][ni] = __builtin_amdgcn_mfma_f32_16x16x32_bf16(af[mi], bfr[ni], acc[mi][ni], 0, 0, 0);

    __builtin_amdgcn_s_barrier();          // reads of buf[cur] done before it is restaged
  }
  #undef GSTAGE

  if (EPI == 0) {
    #pragma unroll
    for (int ni = 0; ni < 4; ++ni) {
      int col = bn * 128 + wn * 64 + ni * 16 + lr;
      float bb = bias[col];
      #pragma unroll
      for (int mi = 0; mi < 4; ++mi) {
        int row = bm * 128 + wm * 64 + mi * 16 + lh * 4;
        #pragma unroll
        for (int r = 0; r < 4; ++r)
          of[(row + r) * (NBN * 128) + col] = acc[mi][ni][r] + bb;
      }
    }
  } else {
    const int s = bn >> 3;                 // third: 0=q, 1=k, 2=v
    __syncthreads();                       // staging LDS dead; reuse for repack
    if (s < 2) {
      // repack [row][col] stride 136 (conflict-free), then coalesced uint4 row stores
      u16* dst = (s == 0) ? oq : ok;
      const float sc = (s == 0) ? QSCALE : 1.0f;
      #pragma unroll
      for (int ni = 0; ni < 4; ++ni) {
        int cl = wn * 64 + ni * 16 + lr;
        float bb = bias[bn * 128 + cl];
        #pragma unroll
        for (int mi = 0; mi < 4; ++mi) {
          int rl = wm * 64 + mi * 16 + lh * 4;
          #pragma unroll
          for (int r = 0; r < 4; ++r)
            lds[(rl + r) * 136 + cl] = f2bf((acc[mi][ni][r] + bb) * sc);
        }
      }
      __syncthreads();
      const int row = tid >> 1, half = tid & 1;
      const int h0 = ((bn * 128) & 1023) >> 6;
      const int b = (bm * 128) >> 10, n0 = (bm * 128) & 1023;
      const u16* srow = lds + row * 136 + half * 64;
      u16* drow = dst + ((u32)((b * 16 + h0 + half) * 1024) + n0 + row) * 64;
      #pragma unroll
      for (int j = 0; j < 8; ++j)
        *(uint4*)(drow + j * 8) = *(const uint4*)(srow + j * 8);
    } else {
      // v: transpose 128x128 tile via LDS (stride 136), write [bh][d][n] coalesced
      #pragma unroll
      for (int ni = 0; ni < 4; ++ni) {
        int cl = wn * 64 + ni * 16 + lr;
        float bb = bias[bn * 128 + cl];
        #pragma unroll
        for (int mi = 0; mi < 4; ++mi) {
          int rl = wm * 64 + mi * 16 + lh * 4;
          u32 p0 = (u32)f2bf(acc[mi][ni][0] + bb) | ((u32)f2bf(acc[mi][ni][1] + bb) << 16);
          u32 p1 = (u32)f2bf(acc[mi][ni][2] + bb) | ((u32)f2bf(acc[mi][ni][3] + bb) << 16);
          uint2 pk; pk.x = p0; pk.y = p1;
          *(uint2*)(lds + cl * 136 + rl) = pk;
        }
      }
      __syncthreads();
      int cl = tid >> 1, half = tid & 1;
      int c = bn * 128 + cl, cc = c & 1023, h = cc >> 6, d = cc & 63;
      int b = (bm * 128) >> 10, n0 = (bm * 128) & 1023;
      const u16* srow = lds + cl * 136 + half * 64;
      u16* drow = ovt + ((b * 16 + h) * 64 + d) * 1024 + n0 + half * 64;
      #pragma unroll
      for (int j = 0; j < 8; ++j)
        *(uint4*)(drow + j * 8) = *(const uint4*)(srow + j * 8);
    }
  }
}

// ---------------- flash attention, swapped-QK^T 32x32 in-register softmax ----------------
// 1 block = (bh, 128-row q-block), 4 waves x 32 q-rows, KVBLK=64, double-buffered K/V.
// q,k: [bh][n][64] bf16 (q pre-scaled by 0.125*log2e); vt: [bh][64][n] bf16; ao: [b][n][h*64+d] bf16
__global__ __launch_bounds__(256) void k_attn(const u16* __restrict__ q, const u16* __restrict__ k,
                                              const u16* __restrict__ vt, u16* __restrict__ ao) {
  __shared__ u16 Ks[2][4096], Vs[2][4096];   // [64 rows][64] bf16, XOR-swizzled, 32 KB total
  const int tid = threadIdx.x, l = tid & 63, w = tid >> 6;
  const int lq = l & 31;          // this lane's q-row within the warp tile (and d-col of O)
  const int hi = l >> 5;          // half-wave
  const int i = blockIdx.x;
  const int bh = (i & 7) * 8 + ((i >> 3) & 7);
  const int qb = i >> 6;          // 0..7

  const int qrow = qb * 128 + w * 32 + lq;
  const u16* qg = q + bh * 65536 + qrow * 64;
  bf16x8 qf[4];
  #pragma unroll
  for (int ks = 0; ks < 4; ++ks)
    qf[ks] = *(const bf16x8*)(qg + ks * 16 + hi * 8);   // Q[qrow][ks*16 + hi*8 + j]

  float mr = -1e30f, lsum = 0.f;
  f32x16 o0 = {}, o1 = {};        // O[q=crow(r,hi)][d = dt*32 + lq]

  const u16* kg = k + bh * 65536;
  const u16* vg = vt + bh * 65536;

  const int ch0 = tid, ch1 = 256 + tid;
  const int r0_ = ch0 >> 3, s0_ = (ch0 & 7) ^ (r0_ & 7);
  const int r1_ = ch1 >> 3, s1_ = (ch1 & 7) ^ (r1_ & 7);

  #define STAGE(t, buf)                                                        \
    do {                                                                       \
      gload_lds16(kg + (t) * 4096 + r0_ * 64 + s0_ * 8, Ks[buf] + ch0 * 8);    \
      gload_lds16(vg + r0_ * 1024 + (t) * 64 + s0_ * 8, Vs[buf] + ch0 * 8);    \
      gload_lds16(kg + (t) * 4096 + r1_ * 64 + s1_ * 8, Ks[buf] + ch1 * 8);    \
      gload_lds16(vg + r1_ * 1024 + (t) * 64 + s1_ * 8, Vs[buf] + ch1 * 8);    \
    } while (0)

  STAGE(0, 0);

  const int swz = (lq & 7) << 4;

  for (int t = 0; t < 16; ++t) {
    const int cur = t & 1;
    if (t < 15) {
      STAGE(t + 1, cur ^ 1);
      asm volatile("s_waitcnt vmcnt(4)" ::: "memory");
    } else {
      asm volatile("s_waitcnt vmcnt(0)" ::: "memory");
    }
    __builtin_amdgcn_s_barrier();
    __builtin_amdgcn_sched_barrier(0);

    // ---- S^T = K * Q^T : lane holds S[q=lq][key = st*32 + crow(r,hi)] ----
    f32x16 sA = {}, sB = {};
    __builtin_amdgcn_s_setprio(1);
    #pragma unroll
    for (int ks = 0; ks < 4; ++ks) {
      bf16x8 kf0 = *(const bf16x8*)((const char*)Ks[cur] + (((lq) * 128 + ks * 32 + hi * 16) ^ swz));
      bf16x8 kf1 = *(const bf16x8*)((const char*)Ks[cur] + (((32 + lq) * 128 + ks * 32 + hi * 16) ^ swz));
      sA = __builtin_amdgcn_mfma_f32_32x32x16_bf16(kf0, qf[ks], sA, 0, 0, 0);
      sB = __builtin_amdgcn_mfma_f32_32x32x16_bf16(kf1, qf[ks], sB, 0, 0, 0);
    }
    __builtin_amdgcn_s_setprio(0);

    // ---- online softmax, fully in-register (scores in log2 domain) ----
    float pmax = sA[0];
    #pragma unroll
    for (int r = 1; r < 16; ++r) pmax = fmaxf(pmax, sA[r]);
    #pragma unroll
    for (int r = 0; r < 16; ++r) pmax = fmaxf(pmax, sB[r]);
    pmax = fmaxf(pmax, __shfl_xor(pmax, 32));

    if (!__all(pmax - mr <= 8.0f)) {        // defer-max (T13): rescale rarely
      float nm = fmaxf(mr, pmax);
      float al = __builtin_amdgcn_exp2f(mr - nm);
      mr = nm;
      lsum *= al;
      #pragma unroll
      for (int r = 0; r < 16; ++r) {
        int row = (r & 3) + 8 * (r >> 2) + 4 * hi;
        float f = __shfl(al, row, 64);
        o0[r] *= f; o1[r] *= f;
      }
    }

    float ls = 0.f;
    #pragma unroll
    for (int r = 0; r < 16; ++r) { float e = __builtin_amdgcn_exp2f(sA[r] - mr); sA[r] = e; ls += e; }
    #pragma unroll
    for (int r = 0; r < 16; ++r) { float e = __builtin_amdgcn_exp2f(sB[r] - mr); sB[r] = e; ls += e; }
    lsum += ls;

    // ---- pack P to bf16 + lo/hi half exchange -> A-fragments pa[4] ----
    u32 wa[8], wb[8];
    #pragma unroll
    for (int j = 0; j < 8; ++j) {
      wa[j] = cvtpk(sA[2 * j], sA[2 * j + 1]);
      wb[j] = cvtpk(sB[2 * j], sB[2 * j + 1]);
    }
    u32 xa0 = __shfl_xor((int)wa[0], 32), xa1 = __shfl_xor((int)wa[1], 32);
    u32 xa2 = __shfl_xor((int)wa[2], 32), xa3 = __shfl_xor((int)wa[3], 32);
    u32 xa4 = __shfl_xor((int)wa[4], 32), xa5 = __shfl_xor((int)wa[5], 32);
    u32 xa6 = __shfl_xor((int)wa[6], 32), xa7 = __shfl_xor((int)wa[7], 32);
    u32 xb0 = __shfl_xor((int)wb[0], 32), xb1 = __shfl_xor((int)wb[1], 32);
    u32 xb2 = __shfl_xor((int)wb[2], 32), xb3 = __shfl_xor((int)wb[3], 32);
    u32 xb4 = __shfl_xor((int)wb[4], 32), xb5 = __shfl_xor((int)wb[5], 32);
    u32 xb6 = __shfl_xor((int)wb[6], 32), xb7 = __shfl_xor((int)wb[7], 32);
    bf16x8 pa0 = mkfrag(hi ? xa2 : wa[0], hi ? xa3 : wa[1], hi ? wa[2] : xa0, hi ? wa[3] : xa1);
    bf16x8 pa1 = mkfrag(hi ? xa6 : wa[4], hi ? xa7 : wa[5], hi ? wa[6] : xa4, hi ? wa[7] : xa5);
    bf16x8 pa2 = mkfrag(hi ? xb2 : wb[0], hi ? xb3 : wb[1], hi ? wb[2] : xb0, hi ? wb[3] : xb1);
    bf16x8 pa3 = mkfrag(hi ? xb6 : wb[4], hi ? xb7 : wb[5], hi ? wb[6] : xb4, hi ? wb[7] : xb5);

    // ---- O += P * V ----
    __builtin_amdgcn_s_setprio(1);
    #pragma unroll
    for (int ks = 0; ks < 4; ++ks) {
      bf16x8 pf = (ks == 0) ? pa0 : (ks == 1) ? pa1 : (ks == 2) ? pa2 : pa3;
      bf16x8 vf0 = *(const bf16x8*)((const char*)Vs[cur] + (((lq) * 128 + ks * 32 + hi * 16) ^ swz));
      bf16x8 vf1 = *(const bf16x8*)((const char*)Vs[cur] + (((32 + lq) * 128 + ks * 32 + hi * 16) ^ swz));
      o0 = __builtin_amdgcn_mfma_f32_32x32x16_bf16(pf, vf0, o0, 0, 0, 0);
      o1 = __builtin_amdgcn_mfma_f32_32x32x16_bf16(pf, vf1, o1, 0, 0, 0);
    }
    __builtin_amdgcn_s_setprio(0);

    __builtin_amdgcn_s_barrier();
  }
  #undef STAGE

  // ---- epilogue: divide by row-sum, coalesced bf16 stores ----
  lsum += __shfl_xor(lsum, 32);
  const int b = bh >> 4, h = bh & 15;
  u16* aob = ao + (u32)(b * 1024 + qb * 128 + w * 32) * 1024 + h * 64;
  #pragma unroll
  for (int r = 0; r < 16; ++r) {
    int row = (r & 3) + 8 * (r >> 2) + 4 * hi;
    float inv = 1.0f / __shfl(lsum, row, 64);
    aob[row * 1024 + lq]      = f2bf(o0[r] * inv);
    aob[row * 1024 + 32 + lq] = f2bf(o1[r] * inv);
  }
}

// ---------------- launch ----------------
extern "C" void kernel_launch(void* const* d_in, const int* in_sizes, int n_in,
                              void* d_out, int out_size, void* d_ws, size_t ws_size,
                              hipStream_t stream) {
  const float* x      = (const float*)d_in[0];
  const float* w_qkv  = (const float*)d_in[1];
  const float* b_qkv  = (const float*)d_in[2];
  const float* w_proj = (const float*)d_in[3];
  const float* b_proj = (const float*)d_in[4];
  float* out = (float*)d_out;
  char* ws = (char*)d_ws;

  u16* X16   = (u16*)ws;                   //  [4096][1024] bf16 (reused as AO later)
  u16* Wqkv  = (u16*)(ws + 8388608);       //  [3072][1024] bf16
  u16* Wproj = (u16*)(ws + 14680064);      //  [1024][1024] bf16
  u16* Q     = (u16*)(ws + 16777216);      //  [64][1024][64]
  u16* K     = (u16*)(ws + 25165824);      //  [64][1024][64]
  u16* VT    = (u16*)(ws + 33554432);      //  [64][64][1024]
  u16* AO    = X16;

  k_cvt_x<<<dim3(2048), dim3(256), 0, stream>>>(x, X16);
  k_transpose_cvt<<<dim3(96, 32), dim3(32, 8), 0, stream>>>(w_qkv, Wqkv, 1024, 3072);
  k_transpose_cvt<<<dim3(32, 32), dim3(32, 8), 0, stream>>>(w_proj, Wproj, 1024, 1024);
  k_gemm<1, 24><<<dim3(768), dim3(256), 0, stream>>>(X16, Wqkv, b_qkv, Q, K, VT, (float*)0);
  k_attn<<<dim3(512), dim3(256), 0, stream>>>(Q, K, VT, AO);
  k_gemm<0, 8><<<dim3(256), dim3(256), 0, stream>>>(AO, Wproj, b_proj, (u16*)0, (u16*)0, (u16*)0, out);
}

// Round 6
// 103.810 us; speedup vs baseline: 1.4362x; 1.1013x over previous
//
#include <hip/hip_runtime.h>

typedef unsigned short u16;
typedef unsigned int u32;
typedef __attribute__((ext_vector_type(8))) short bf16x8;
typedef __attribute__((ext_vector_type(4))) float f32x4;
typedef __attribute__((ext_vector_type(16))) float f32x16;

#define LOG2E 1.4426950408889634f
#define QSCALE (0.125f * LOG2E)

__device__ __forceinline__ u16 f2bf(float f) {
  union { float f; u32 u; } x; x.f = f;
  u32 r = x.u + 0x7fffu + ((x.u >> 16) & 1u);   // RNE; inputs are finite
  return (u16)(r >> 16);
}

__device__ __forceinline__ u32 cvtpk(float a, float b) {
  u32 r;
  asm("v_cvt_pk_bf16_f32 %0, %1, %2" : "=v"(r) : "v"(a), "v"(b));
  return r;
}

__device__ __forceinline__ bf16x8 mkfrag(u32 a, u32 b, u32 c, u32 d) {
  union { u32 w[4]; bf16x8 v; } u;
  u.w[0] = a; u.w[1] = b; u.w[2] = c; u.w[3] = d;
  return u.v;
}

__device__ __forceinline__ void gload_lds16(const void* g, void* l) {
  __builtin_amdgcn_global_load_lds((const __attribute__((address_space(1))) u32*)g,
                                   (__attribute__((address_space(3))) u32*)l, 16, 0, 0);
}

// ---------------- prep: fp32 -> bf16 (x), 8 elems/thread ----------------
__global__ __launch_bounds__(256) void k_cvt_x(const float* __restrict__ in, u16* __restrict__ out) {
  int i = blockIdx.x * 256 + threadIdx.x;
  const float4* p = (const float4*)in;
  float4 a = p[i * 2], b = p[i * 2 + 1];
  uint4 o;
  o.x = (u32)f2bf(a.x) | ((u32)f2bf(a.y) << 16);
  o.y = (u32)f2bf(a.z) | ((u32)f2bf(a.w) << 16);
  o.z = (u32)f2bf(b.x) | ((u32)f2bf(b.y) << 16);
  o.w = (u32)f2bf(b.z) | ((u32)f2bf(b.w) << 16);
  ((uint4*)out)[i] = o;
}

// ---------------- prep: transpose + convert: src[R][Cc] f32 -> dst[Cc][R] bf16 ----------------
__global__ __launch_bounds__(256) void k_transpose_cvt(const float* __restrict__ src, u16* __restrict__ dst,
                                                       int R, int Cc) {
  __shared__ float tile[32][33];
  int c0 = blockIdx.x * 32, r0 = blockIdx.y * 32;
  int tx = threadIdx.x, ty = threadIdx.y;   // (32,8)
  #pragma unroll
  for (int j = 0; j < 4; ++j)
    tile[ty * 4 + j][tx] = src[(r0 + ty * 4 + j) * Cc + c0 + tx];
  __syncthreads();
  #pragma unroll
  for (int j = 0; j < 4; ++j) {
    int cl = ty * 4 + j;
    dst[(c0 + cl) * R + r0 + tx] = f2bf(tile[tx][cl]);
  }
}

// ---------------- 128x128 bf16 GEMM, K=1024, BK=32, depth-2 prefetch (3 LDS bufs), 1 barrier/iter --
// A  : [M][1024] bf16 row-major;  Bt : [N][1024] bf16 row-major (Bt[n][k])
// EPI 0: of[m][col] = acc + bias[col]  (fp32, N=NBN*128)
// EPI 1: qkv: cols [0,1024)->q (scaled, [bh][n][64]), [1024,2048)->k, [2048,3072)->vt ([bh][d][n])
template <int EPI, int NBN>
__global__ __launch_bounds__(256) void k_gemm(const u16* __restrict__ A, const u16* __restrict__ Bt,
                                              const float* __restrict__ bias,
                                              u16* __restrict__ oq, u16* __restrict__ ok,
                                              u16* __restrict__ ovt, float* __restrict__ of) {
  __shared__ u16 lds[24576];                 // 3 staging bufs x 16 KB; EPI1 repack reuses 34816 B
  const int tid = threadIdx.x;
  const int l = tid & 63, w = tid >> 6;
  const int wm = w >> 1, wn = w & 1;
  const int lr = l & 15, lh = l >> 4;
  // bijective XCD chunk swizzle (gridDim.x % 8 == 0)
  const int cpx = gridDim.x >> 3;
  const int wg = (blockIdx.x & 7) * cpx + (blockIdx.x >> 3);
  const int bn = wg % NBN, bm = wg / NBN;

  f32x4 acc[4][4] = {};
  const int e = tid * 8;                    // staging element idx; row=e>>5, col=e&31
  const u16* gA = A + (bm * 128 + (e >> 5)) * 1024 + (e & 31);
  const u16* gB = Bt + (bn * 128 + (e >> 5)) * 1024 + (e & 31);

  #define GSTAGE(kk, b)                                              \
    do {                                                             \
      gload_lds16(gA + (kk),         lds + (b) * 8192 + e);          \
      gload_lds16(gA + (kk) + 65536, lds + (b) * 8192 + e + 2048);   \
      gload_lds16(gB + (kk),         lds + (b) * 8192 + 4096 + e);   \
      gload_lds16(gB + (kk) + 65536, lds + (b) * 8192 + 4096 + e + 2048); \
    } while (0)

  GSTAGE(0, 0);
  GSTAGE(32, 1);
  int cur = 0, nxt = 2;                     // nxt = (it+2)%3 tracked incrementally

  for (int it = 0; it < 32; ++it) {
    // wait my tile-t loads (issued 2 iters ago; t+1's 4 may remain in flight)
    if (it < 31) asm volatile("s_waitcnt vmcnt(4)" ::: "memory");
    else         asm volatile("s_waitcnt vmcnt(0)" ::: "memory");
    // all waves: (a) passed their own vmcnt for tile t -> tile t complete in LDS;
    // (b) finished compute of t-1 -> restaging buf[(t+2)%3]==buf[(t-1)%3] is race-free.
    __builtin_amdgcn_s_barrier();
    __builtin_amdgcn_sched_barrier(0);

    if (it < 30) GSTAGE((it + 2) * 32, nxt);

    const u16* Asc = lds + cur * 8192;
    const u16* Bsc = lds + cur * 8192 + 4096;
    bf16x8 af[4], bfr[4];
    #pragma unroll
    for (int mi = 0; mi < 4; ++mi)
      af[mi] = *(const bf16x8*)(Asc + (wm * 64 + mi * 16 + lr) * 32 + lh * 8);
    #pragma unroll
    for (int ni = 0; ni < 4; ++ni)
      bfr[ni] = *(const bf16x8*)(Bsc + (wn * 64 + ni * 16 + lr) * 32 + lh * 8);
    #pragma unroll
    for (int mi = 0; mi < 4; ++mi)
      #pragma unroll
      for (int ni = 0; ni < 4; ++ni)
        acc[mi][ni] = __builtin_amdgcn_mfma_f32_16x16x32_bf16(af[mi], bfr[ni], acc[mi][ni], 0, 0, 0);

    cur = (cur == 2) ? 0 : cur + 1;
    nxt = (nxt == 2) ? 0 : nxt + 1;
  }
  #undef GSTAGE

  if (EPI == 0) {
    #pragma unroll
    for (int ni = 0; ni < 4; ++ni) {
      int col = bn * 128 + wn * 64 + ni * 16 + lr;
      float bb = bias[col];
      #pragma unroll
      for (int mi = 0; mi < 4; ++mi) {
        int row = bm * 128 + wm * 64 + mi * 16 + lh * 4;
        #pragma unroll
        for (int r = 0; r < 4; ++r)
          of[(row + r) * (NBN * 128) + col] = acc[mi][ni][r] + bb;
      }
    }
  } else {
    const int s = bn >> 3;                 // third: 0=q, 1=k, 2=v
    __syncthreads();                       // staging LDS dead; reuse for repack
    if (s < 2) {
      // repack [row][col] stride 136 (conflict-free), then coalesced uint4 row stores
      u16* dst = (s == 0) ? oq : ok;
      const float sc = (s == 0) ? QSCALE : 1.0f;
      #pragma unroll
      for (int ni = 0; ni < 4; ++ni) {
        int cl = wn * 64 + ni * 16 + lr;
        float bb = bias[bn * 128 + cl];
        #pragma unroll
        for (int mi = 0; mi < 4; ++mi) {
          int rl = wm * 64 + mi * 16 + lh * 4;
          #pragma unroll
          for (int r = 0; r < 4; ++r)
            lds[(rl + r) * 136 + cl] = f2bf((acc[mi][ni][r] + bb) * sc);
        }
      }
      __syncthreads();
      const int row = tid >> 1, half = tid & 1;
      const int h0 = ((bn * 128) & 1023) >> 6;
      const int b = (bm * 128) >> 10, n0 = (bm * 128) & 1023;
      const u16* srow = lds + row * 136 + half * 64;
      u16* drow = dst + ((u32)((b * 16 + h0 + half) * 1024) + n0 + row) * 64;
      #pragma unroll
      for (int j = 0; j < 8; ++j)
        *(uint4*)(drow + j * 8) = *(const uint4*)(srow + j * 8);
    } else {
      // v: transpose 128x128 tile via LDS (stride 136), write [bh][d][n] coalesced
      #pragma unroll
      for (int ni = 0; ni < 4; ++ni) {
        int cl = wn * 64 + ni * 16 + lr;
        float bb = bias[bn * 128 + cl];
        #pragma unroll
        for (int mi = 0; mi < 4; ++mi) {
          int rl = wm * 64 + mi * 16 + lh * 4;
          u32 p0 = (u32)f2bf(acc[mi][ni][0] + bb) | ((u32)f2bf(acc[mi][ni][1] + bb) << 16);
          u32 p1 = (u32)f2bf(acc[mi][ni][2] + bb) | ((u32)f2bf(acc[mi][ni][3] + bb) << 16);
          uint2 pk; pk.x = p0; pk.y = p1;
          *(uint2*)(lds + cl * 136 + rl) = pk;
        }
      }
      __syncthreads();
      int cl = tid >> 1, half = tid & 1;
      int c = bn * 128 + cl, cc = c & 1023, h = cc >> 6, d = cc & 63;
      int b = (bm * 128) >> 10, n0 = (bm * 128) & 1023;
      const u16* srow = lds + cl * 136 + half * 64;
      u16* drow = ovt + ((b * 16 + h) * 64 + d) * 1024 + n0 + half * 64;
      #pragma unroll
      for (int j = 0; j < 8; ++j)
        *(uint4*)(drow + j * 8) = *(const uint4*)(srow + j * 8);
    }
  }
}

// ---------------- flash attention, swapped-QK^T 32x32 in-register softmax ----------------
// 1 block = (bh, 128-row q-block), 4 waves x 32 q-rows, KVBLK=64, double-buffered K/V.
// q,k: [bh][n][64] bf16 (q pre-scaled by 0.125*log2e); vt: [bh][64][n] bf16; ao: [b][n][h*64+d] bf16
__global__ __launch_bounds__(256) void k_attn(const u16* __restrict__ q, const u16* __restrict__ k,
                                              const u16* __restrict__ vt, u16* __restrict__ ao) {
  __shared__ u16 Ks[2][4096], Vs[2][4096];   // [64 rows][64] bf16, XOR-swizzled, 32 KB total
  const int tid = threadIdx.x, l = tid & 63, w = tid >> 6;
  const int lq = l & 31;          // this lane's q-row within the warp tile (and d-col of O)
  const int hi = l >> 5;          // half-wave
  const int i = blockIdx.x;
  const int bh = (i & 7) * 8 + ((i >> 3) & 7);
  const int qb = i >> 6;          // 0..7

  const int qrow = qb * 128 + w * 32 + lq;
  const u16* qg = q + bh * 65536 + qrow * 64;
  bf16x8 qf[4];
  #pragma unroll
  for (int ks = 0; ks < 4; ++ks)
    qf[ks] = *(const bf16x8*)(qg + ks * 16 + hi * 8);   // Q[qrow][ks*16 + hi*8 + j]

  float mr = -1e30f, lsum = 0.f;
  f32x16 o0 = {}, o1 = {};        // O[q=crow(r,hi)][d = dt*32 + lq]

  const u16* kg = k + bh * 65536;
  const u16* vg = vt + bh * 65536;

  const int ch0 = tid, ch1 = 256 + tid;
  const int r0_ = ch0 >> 3, s0_ = (ch0 & 7) ^ (r0_ & 7);
  const int r1_ = ch1 >> 3, s1_ = (ch1 & 7) ^ (r1_ & 7);

  #define STAGE(t, buf)                                                        \
    do {                                                                       \
      gload_lds16(kg + (t) * 4096 + r0_ * 64 + s0_ * 8, Ks[buf] + ch0 * 8);    \
      gload_lds16(vg + r0_ * 1024 + (t) * 64 + s0_ * 8, Vs[buf] + ch0 * 8);    \
      gload_lds16(kg + (t) * 4096 + r1_ * 64 + s1_ * 8, Ks[buf] + ch1 * 8);    \
      gload_lds16(vg + r1_ * 1024 + (t) * 64 + s1_ * 8, Vs[buf] + ch1 * 8);    \
    } while (0)

  STAGE(0, 0);

  const int swz = (lq & 7) << 4;

  for (int t = 0; t < 16; ++t) {
    const int cur = t & 1;
    if (t < 15) {
      STAGE(t + 1, cur ^ 1);
      asm volatile("s_waitcnt vmcnt(4)" ::: "memory");
    } else {
      asm volatile("s_waitcnt vmcnt(0)" ::: "memory");
    }
    __builtin_amdgcn_s_barrier();
    __builtin_amdgcn_sched_barrier(0);

    // ---- S^T = K * Q^T : lane holds S[q=lq][key = st*32 + crow(r,hi)] ----
    f32x16 sA = {}, sB = {};
    __builtin_amdgcn_s_setprio(1);
    #pragma unroll
    for (int ks = 0; ks < 4; ++ks) {
      bf16x8 kf0 = *(const bf16x8*)((const char*)Ks[cur] + (((lq) * 128 + ks * 32 + hi * 16) ^ swz));
      bf16x8 kf1 = *(const bf16x8*)((const char*)Ks[cur] + (((32 + lq) * 128 + ks * 32 + hi * 16) ^ swz));
      sA = __builtin_amdgcn_mfma_f32_32x32x16_bf16(kf0, qf[ks], sA, 0, 0, 0);
      sB = __builtin_amdgcn_mfma_f32_32x32x16_bf16(kf1, qf[ks], sB, 0, 0, 0);
    }
    __builtin_amdgcn_s_setprio(0);

    // ---- online softmax, fully in-register (scores in log2 domain) ----
    float pmax = sA[0];
    #pragma unroll
    for (int r = 1; r < 16; ++r) pmax = fmaxf(pmax, sA[r]);
    #pragma unroll
    for (int r = 0; r < 16; ++r) pmax = fmaxf(pmax, sB[r]);
    pmax = fmaxf(pmax, __shfl_xor(pmax, 32));

    if (!__all(pmax - mr <= 8.0f)) {        // defer-max (T13): rescale rarely
      float nm = fmaxf(mr, pmax);
      float al = __builtin_amdgcn_exp2f(mr - nm);
      mr = nm;
      lsum *= al;
      #pragma unroll
      for (int r = 0; r < 16; ++r) {
        int row = (r & 3) + 8 * (r >> 2) + 4 * hi;
        float f = __shfl(al, row, 64);
        o0[r] *= f; o1[r] *= f;
      }
    }

    float ls = 0.f;
    #pragma unroll
    for (int r = 0; r < 16; ++r) { float e = __builtin_amdgcn_exp2f(sA[r] - mr); sA[r] = e; ls += e; }
    #pragma unroll
    for (int r = 0; r < 16; ++r) { float e = __builtin_amdgcn_exp2f(sB[r] - mr); sB[r] = e; ls += e; }
    lsum += ls;

    // ---- pack P to bf16 + lo/hi half exchange -> A-fragments pa[4] ----
    u32 wa[8], wb[8];
    #pragma unroll
    for (int j = 0; j < 8; ++j) {
      wa[j] = cvtpk(sA[2 * j], sA[2 * j + 1]);
      wb[j] = cvtpk(sB[2 * j], sB[2 * j + 1]);
    }
    u32 xa0 = __shfl_xor((int)wa[0], 32), xa1 = __shfl_xor((int)wa[1], 32);
    u32 xa2 = __shfl_xor((int)wa[2], 32), xa3 = __shfl_xor((int)wa[3], 32);
    u32 xa4 = __shfl_xor((int)wa[4], 32), xa5 = __shfl_xor((int)wa[5], 32);
    u32 xa6 = __shfl_xor((int)wa[6], 32), xa7 = __shfl_xor((int)wa[7], 32);
    u32 xb0 = __shfl_xor((int)wb[0], 32), xb1 = __shfl_xor((int)wb[1], 32);
    u32 xb2 = __shfl_xor((int)wb[2], 32), xb3 = __shfl_xor((int)wb[3], 32);
    u32 xb4 = __shfl_xor((int)wb[4], 32), xb5 = __shfl_xor((int)wb[5], 32);
    u32 xb6 = __shfl_xor((int)wb[6], 32), xb7 = __shfl_xor((int)wb[7], 32);
    bf16x8 pa0 = mkfrag(hi ? xa2 : wa[0], hi ? xa3 : wa[1], hi ? wa[2] : xa0, hi ? wa[3] : xa1);
    bf16x8 pa1 = mkfrag(hi ? xa6 : wa[4], hi ? xa7 : wa[5], hi ? wa[6] : xa4, hi ? wa[7] : xa5);
    bf16x8 pa2 = mkfrag(hi ? xb2 : wb[0], hi ? xb3 : wb[1], hi ? wb[2] : xb0, hi ? wb[3] : xb1);
    bf16x8 pa3 = mkfrag(hi ? xb6 : wb[4], hi ? xb7 : wb[5], hi ? wb[6] : xb4, hi ? wb[7] : xb5);

    // ---- O += P * V ----
    __builtin_amdgcn_s_setprio(1);
    #pragma unroll
    for (int ks = 0; ks < 4; ++ks) {
      bf16x8 pf = (ks == 0) ? pa0 : (ks == 1) ? pa1 : (ks == 2) ? pa2 : pa3;
      bf16x8 vf0 = *(const bf16x8*)((const char*)Vs[cur] + (((lq) * 128 + ks * 32 + hi * 16) ^ swz));
      bf16x8 vf1 = *(const bf16x8*)((const char*)Vs[cur] + (((32 + lq) * 128 + ks * 32 + hi * 16) ^ swz));
      o0 = __builtin_amdgcn_mfma_f32_32x32x16_bf16(pf, vf0, o0, 0, 0, 0);
      o1 = __builtin_amdgcn_mfma_f32_32x32x16_bf16(pf, vf1, o1, 0, 0, 0);
    }
    __builtin_amdgcn_s_setprio(0);

    __builtin_amdgcn_s_barrier();
  }
  #undef STAGE

  // ---- epilogue: divide by row-sum, coalesced bf16 stores ----
  lsum += __shfl_xor(lsum, 32);
  const int b = bh >> 4, h = bh & 15;
  u16* aob = ao + (u32)(b * 1024 + qb * 128 + w * 32) * 1024 + h * 64;
  #pragma unroll
  for (int r = 0; r < 16; ++r) {
    int row = (r & 3) + 8 * (r >> 2) + 4 * hi;
    float inv = 1.0f / __shfl(lsum, row, 64);
    aob[row * 1024 + lq]      = f2bf(o0[r] * inv);
    aob[row * 1024 + 32 + lq] = f2bf(o1[r] * inv);
  }
}

// ---------------- launch ----------------
extern "C" void kernel_launch(void* const* d_in, const int* in_sizes, int n_in,
                              void* d_out, int out_size, void* d_ws, size_t ws_size,
                              hipStream_t stream) {
  const float* x      = (const float*)d_in[0];
  const float* w_qkv  = (const float*)d_in[1];
  const float* b_qkv  = (const float*)d_in[2];
  const float* w_proj = (const float*)d_in[3];
  const float* b_proj = (const float*)d_in[4];
  float* out = (float*)d_out;
  char* ws = (char*)d_ws;

  u16* X16   = (u16*)ws;                   //  [4096][1024] bf16 (reused as AO later)
  u16* Wqkv  = (u16*)(ws + 8388608);       //  [3072][1024] bf16
  u16* Wproj = (u16*)(ws + 14680064);      //  [1024][1024] bf16
  u16* Q     = (u16*)(ws + 16777216);      //  [64][1024][64]
  u16* K     = (u16*)(ws + 25165824);      //  [64][1024][64]
  u16* VT    = (u16*)(ws + 33554432);      //  [64][64][1024]
  u16* AO    = X16;

  k_cvt_x<<<dim3(2048), dim3(256), 0, stream>>>(x, X16);
  k_transpose_cvt<<<dim3(96, 32), dim3(32, 8), 0, stream>>>(w_qkv, Wqkv, 1024, 3072);
  k_transpose_cvt<<<dim3(32, 32), dim3(32, 8), 0, stream>>>(w_proj, Wproj, 1024, 1024);
  k_gemm<1, 24><<<dim3(768), dim3(256), 0, stream>>>(X16, Wqkv, b_qkv, Q, K, VT, (float*)0);
  k_attn<<<dim3(512), dim3(256), 0, stream>>>(Q, K, VT, AO);
  k_gemm<0, 8><<<dim3(256), dim3(256), 0, stream>>>(AO, Wproj, b_proj, (u16*)0, (u16*)0, (u16*)0, out);
}

// Round 7
// 99.873 us; speedup vs baseline: 1.4929x; 1.0394x over previous
//
#include <hip/hip_runtime.h>

typedef unsigned short u16;
typedef unsigned int u32;
typedef __attribute__((ext_vector_type(8))) short bf16x8;
typedef __attribute__((ext_vector_type(4))) float f32x4;
typedef __attribute__((ext_vector_type(16))) float f32x16;

#define LOG2E 1.4426950408889634f
#define QSCALE (0.125f * LOG2E)

__device__ __forceinline__ u16 f2bf(float f) {
  union { float f; u32 u; } x; x.f = f;
  u32 r = x.u + 0x7fffu + ((x.u >> 16) & 1u);   // RNE; inputs are finite
  return (u16)(r >> 16);
}

__device__ __forceinline__ u32 cvtpk(float a, float b) {
  u32 r;
  asm("v_cvt_pk_bf16_f32 %0, %1, %2" : "=v"(r) : "v"(a), "v"(b));
  return r;
}

__device__ __forceinline__ bf16x8 mkfrag(u32 a, u32 b, u32 c, u32 d) {
  union { u32 w[4]; bf16x8 v; } u;
  u.w[0] = a; u.w[1] = b; u.w[2] = c; u.w[3] = d;
  return u.v;
}

__device__ __forceinline__ void gload_lds16(const void* g, void* l) {
  __builtin_amdgcn_global_load_lds((const __attribute__((address_space(1))) u32*)g,
                                   (__attribute__((address_space(3))) u32*)l, 16, 0, 0);
}

// ---------------- prep: fp32 -> bf16 (x), 8 elems/thread ----------------
__global__ __launch_bounds__(256) void k_cvt_x(const float* __restrict__ in, u16* __restrict__ out) {
  int i = blockIdx.x * 256 + threadIdx.x;
  const float4* p = (const float4*)in;
  float4 a = p[i * 2], b = p[i * 2 + 1];
  uint4 o;
  o.x = (u32)f2bf(a.x) | ((u32)f2bf(a.y) << 16);
  o.y = (u32)f2bf(a.z) | ((u32)f2bf(a.w) << 16);
  o.z = (u32)f2bf(b.x) | ((u32)f2bf(b.y) << 16);
  o.w = (u32)f2bf(b.z) | ((u32)f2bf(b.w) << 16);
  ((uint4*)out)[i] = o;
}

// ---------------- prep: transpose + convert: src[R][Cc] f32 -> dst[Cc][R] bf16 ----------------
__global__ __launch_bounds__(256) void k_transpose_cvt(const float* __restrict__ src, u16* __restrict__ dst,
                                                       int R, int Cc) {
  __shared__ float tile[32][33];
  int c0 = blockIdx.x * 32, r0 = blockIdx.y * 32;
  int tx = threadIdx.x, ty = threadIdx.y;   // (32,8)
  #pragma unroll
  for (int j = 0; j < 4; ++j)
    tile[ty * 4 + j][tx] = src[(r0 + ty * 4 + j) * Cc + c0 + tx];
  __syncthreads();
  #pragma unroll
  for (int j = 0; j < 4; ++j) {
    int cl = ty * 4 + j;
    dst[(c0 + cl) * R + r0 + tx] = f2bf(tile[tx][cl]);
  }
}

// -------- 128x128 bf16 GEMM, K=1024, BK=32, 8 waves, depth-2 prefetch (3 bufs), swizzled LDS -----
// A  : [M][1024] bf16 row-major;  Bt : [N][1024] bf16 row-major (Bt[n][k])
// LDS tile layout: [row][granule^((row>>1)&3)] at 16B granules (linear dest for gload_lds,
// pre-swizzled global source; frag reads apply same XOR -> conflict-free, rule 21).
// EPI 0: of[m][col] = acc + bias[col]  (fp32, N=NBN*128)
// EPI 1: qkv: cols [0,1024)->q (scaled, [bh][n][64]), [1024,2048)->k, [2048,3072)->vt ([bh][d][n])
template <int EPI, int NBN>
__global__ __launch_bounds__(512) void k_gemm(const u16* __restrict__ A, const u16* __restrict__ Bt,
                                              const float* __restrict__ bias,
                                              u16* __restrict__ oq, u16* __restrict__ ok,
                                              u16* __restrict__ ovt, float* __restrict__ of) {
  __shared__ u16 lds[24576];                 // 3 staging bufs x 16 KB; EPI1 repack reuses 34816 B
  const int tid = threadIdx.x;
  const int l = tid & 63, w = tid >> 6;      // 8 waves
  const int wm = w >> 2, wn = w & 3;         // 2M x 4N; per-wave 64x32 output
  const int lr = l & 15, lh = l >> 4;
  // bijective XCD chunk swizzle (gridDim.x % 8 == 0)
  const int cpx = gridDim.x >> 3;
  const int wg = (blockIdx.x & 7) * cpx + (blockIdx.x >> 3);
  const int bn = wg % NBN, bm = wg / NBN;

  f32x4 acc[4][2] = {};
  const int e = tid * 8;                     // staging element idx; covers one 128x32 tile
  const int srow = e >> 5;                   // 0..127
  const int sgr  = (e >> 3) & 3;             // 16B granule within 64B row
  const int scol = (sgr ^ ((srow >> 1) & 3)) * 8;   // pre-swizzled source column
  const u16* gA = A + (bm * 128 + srow) * 1024 + scol;
  const u16* gB = Bt + (bn * 128 + srow) * 1024 + scol;

  #define GSTAGE(kk, b)                                              \
    do {                                                             \
      gload_lds16(gA + (kk), lds + (b) * 8192 + e);                  \
      gload_lds16(gB + (kk), lds + (b) * 8192 + 4096 + e);           \
    } while (0)

  GSTAGE(0, 0);
  GSTAGE(32, 1);
  int cur = 0, nxt = 2;                      // nxt = (it+2)%3 tracked incrementally

  for (int it = 0; it < 32; ++it) {
    // wait my tile-t loads (issued 2 iters ago; t+1's 2 may remain in flight)
    if (it < 31) asm volatile("s_waitcnt vmcnt(2)" ::: "memory");
    else         asm volatile("s_waitcnt vmcnt(0)" ::: "memory");
    // all waves passed their own vmcnt for tile t -> tile t complete in LDS;
    // all finished compute t-1 -> restaging buf[(t+2)%3]==buf[(t-1)%3] is race-free.
    __builtin_amdgcn_s_barrier();
    __builtin_amdgcn_sched_barrier(0);

    if (it < 30) GSTAGE((it + 2) * 32, nxt);

    const u16* Asc = lds + cur * 8192;
    bf16x8 af[4], bfr[2];
    #pragma unroll
    for (int mi = 0; mi < 4; ++mi) {
      int r = wm * 64 + mi * 16 + lr;
      af[mi] = *(const bf16x8*)(Asc + r * 32 + ((lh ^ ((r >> 1) & 3)) * 8));
    }
    #pragma unroll
    for (int ni = 0; ni < 2; ++ni) {
      int r = wn * 32 + ni * 16 + lr;
      bfr[ni] = *(const bf16x8*)(Asc + 4096 + r * 32 + ((lh ^ ((r >> 1) & 3)) * 8));
    }
    #pragma unroll
    for (int mi = 0; mi < 4; ++mi)
      #pragma unroll
      for (int ni = 0; ni < 2; ++ni)
        acc[mi][ni] = __builtin_amdgcn_mfma_f32_16x16x32_bf16(af[mi], bfr[ni], acc[mi][ni], 0, 0, 0);

    cur = (cur == 2) ? 0 : cur + 1;
    nxt = (nxt == 2) ? 0 : nxt + 1;
  }
  #undef GSTAGE

  if (EPI == 0) {
    #pragma unroll
    for (int ni = 0; ni < 2; ++ni) {
      int col = bn * 128 + wn * 32 + ni * 16 + lr;
      float bb = bias[col];
      #pragma unroll
      for (int mi = 0; mi < 4; ++mi) {
        int row = bm * 128 + wm * 64 + mi * 16 + lh * 4;
        #pragma unroll
        for (int r = 0; r < 4; ++r)
          of[(row + r) * (NBN * 128) + col] = acc[mi][ni][r] + bb;
      }
    }
  } else {
    const int s = bn >> 3;                 // third: 0=q, 1=k, 2=v
    __syncthreads();                       // staging LDS dead; reuse for repack
    if (s < 2) {
      // repack [row][col] stride 136 (conflict-free), then coalesced uint4 row stores
      u16* dst = (s == 0) ? oq : ok;
      const float sc = (s == 0) ? QSCALE : 1.0f;
      #pragma unroll
      for (int ni = 0; ni < 2; ++ni) {
        int cl = wn * 32 + ni * 16 + lr;
        float bb = bias[bn * 128 + cl];
        #pragma unroll
        for (int mi = 0; mi < 4; ++mi) {
          int rl = wm * 64 + mi * 16 + lh * 4;
          #pragma unroll
          for (int r = 0; r < 4; ++r)
            lds[(rl + r) * 136 + cl] = f2bf((acc[mi][ni][r] + bb) * sc);
        }
      }
      __syncthreads();
      const int row = tid >> 2, q4 = tid & 3;             // 32 cols per thread
      const int h0 = ((bn * 128) & 1023) >> 6;
      const int b = (bm * 128) >> 10, n0 = (bm * 128) & 1023;
      const u16* srow2 = lds + row * 136 + q4 * 32;
      u16* drow = dst + ((u32)((b * 16 + h0 + (q4 >> 1)) * 1024) + n0 + row) * 64 + (q4 & 1) * 32;
      #pragma unroll
      for (int j = 0; j < 4; ++j)
        *(uint4*)(drow + j * 8) = *(const uint4*)(srow2 + j * 8);
    } else {
      // v: transpose 128x128 tile via LDS (stride 136), write [bh][d][n] coalesced
      #pragma unroll
      for (int ni = 0; ni < 2; ++ni) {
        int cl = wn * 32 + ni * 16 + lr;
        float bb = bias[bn * 128 + cl];
        #pragma unroll
        for (int mi = 0; mi < 4; ++mi) {
          int rl = wm * 64 + mi * 16 + lh * 4;
          u32 p0 = (u32)f2bf(acc[mi][ni][0] + bb) | ((u32)f2bf(acc[mi][ni][1] + bb) << 16);
          u32 p1 = (u32)f2bf(acc[mi][ni][2] + bb) | ((u32)f2bf(acc[mi][ni][3] + bb) << 16);
          uint2 pk; pk.x = p0; pk.y = p1;
          *(uint2*)(lds + cl * 136 + rl) = pk;
        }
      }
      __syncthreads();
      const int cl = tid >> 2, q4 = tid & 3;              // 32 n-elems per thread
      const int c = bn * 128 + cl, cc = c & 1023, h = cc >> 6, d = cc & 63;
      const int b = (bm * 128) >> 10, n0 = (bm * 128) & 1023;
      const u16* srow2 = lds + cl * 136 + q4 * 32;
      u16* drow = ovt + ((b * 16 + h) * 64 + d) * 1024 + n0 + q4 * 32;
      #pragma unroll
      for (int j = 0; j < 4; ++j)
        *(uint4*)(drow + j * 8) = *(const uint4*)(srow2 + j * 8);
    }
  }
}

// ---------------- flash attention, swapped-QK^T 32x32 in-register softmax ----------------
// 1 block = (bh, 128-row q-block), 4 waves x 32 q-rows, KVBLK=64, double-buffered K/V.
// q,k: [bh][n][64] bf16 (q pre-scaled by 0.125*log2e); vt: [bh][64][n] bf16; ao: [b][n][h*64+d] bf16
__global__ __launch_bounds__(256) void k_attn(const u16* __restrict__ q, const u16* __restrict__ k,
                                              const u16* __restrict__ vt, u16* __restrict__ ao) {
  __shared__ u16 Ks[2][4096], Vs[2][4096];   // [64 rows][64] bf16, XOR-swizzled, 32 KB total
  const int tid = threadIdx.x, l = tid & 63, w = tid >> 6;
  const int lq = l & 31;          // this lane's q-row within the warp tile (and d-col of O)
  const int hi = l >> 5;          // half-wave
  const int i = blockIdx.x;
  const int bh = (i & 7) * 8 + ((i >> 3) & 7);
  const int qb = i >> 6;          // 0..7

  const int qrow = qb * 128 + w * 32 + lq;
  const u16* qg = q + bh * 65536 + qrow * 64;
  bf16x8 qf[4];
  #pragma unroll
  for (int ks = 0; ks < 4; ++ks)
    qf[ks] = *(const bf16x8*)(qg + ks * 16 + hi * 8);   // Q[qrow][ks*16 + hi*8 + j]

  float mr = -1e30f, lsum = 0.f;
  f32x16 o0 = {}, o1 = {};        // O[q=crow(r,hi)][d = dt*32 + lq]

  const u16* kg = k + bh * 65536;
  const u16* vg = vt + bh * 65536;

  const int ch0 = tid, ch1 = 256 + tid;
  const int r0_ = ch0 >> 3, s0_ = (ch0 & 7) ^ (r0_ & 7);
  const int r1_ = ch1 >> 3, s1_ = (ch1 & 7) ^ (r1_ & 7);

  #define STAGE(t, buf)                                                        \
    do {                                                                       \
      gload_lds16(kg + (t) * 4096 + r0_ * 64 + s0_ * 8, Ks[buf] + ch0 * 8);    \
      gload_lds16(vg + r0_ * 1024 + (t) * 64 + s0_ * 8, Vs[buf] + ch0 * 8);    \
      gload_lds16(kg + (t) * 4096 + r1_ * 64 + s1_ * 8, Ks[buf] + ch1 * 8);    \
      gload_lds16(vg + r1_ * 1024 + (t) * 64 + s1_ * 8, Vs[buf] + ch1 * 8);    \
    } while (0)

  STAGE(0, 0);

  const int swz = (lq & 7) << 4;

  for (int t = 0; t < 16; ++t) {
    const int cur = t & 1;
    if (t < 15) {
      STAGE(t + 1, cur ^ 1);
      asm volatile("s_waitcnt vmcnt(4)" ::: "memory");
    } else {
      asm volatile("s_waitcnt vmcnt(0)" ::: "memory");
    }
    __builtin_amdgcn_s_barrier();
    __builtin_amdgcn_sched_barrier(0);

    // ---- S^T = K * Q^T : lane holds S[q=lq][key = st*32 + crow(r,hi)] ----
    f32x16 sA = {}, sB = {};
    __builtin_amdgcn_s_setprio(1);
    #pragma unroll
    for (int ks = 0; ks < 4; ++ks) {
      bf16x8 kf0 = *(const bf16x8*)((const char*)Ks[cur] + (((lq) * 128 + ks * 32 + hi * 16) ^ swz));
      bf16x8 kf1 = *(const bf16x8*)((const char*)Ks[cur] + (((32 + lq) * 128 + ks * 32 + hi * 16) ^ swz));
      sA = __builtin_amdgcn_mfma_f32_32x32x16_bf16(kf0, qf[ks], sA, 0, 0, 0);
      sB = __builtin_amdgcn_mfma_f32_32x32x16_bf16(kf1, qf[ks], sB, 0, 0, 0);
    }
    __builtin_amdgcn_s_setprio(0);

    // ---- online softmax, fully in-register (scores in log2 domain) ----
    float pmax = sA[0];
    #pragma unroll
    for (int r = 1; r < 16; ++r) pmax = fmaxf(pmax, sA[r]);
    #pragma unroll
    for (int r = 0; r < 16; ++r) pmax = fmaxf(pmax, sB[r]);
    pmax = fmaxf(pmax, __shfl_xor(pmax, 32));

    if (!__all(pmax - mr <= 8.0f)) {        // defer-max (T13): rescale rarely
      float nm = fmaxf(mr, pmax);
      float al = __builtin_amdgcn_exp2f(mr - nm);
      mr = nm;
      lsum *= al;
      #pragma unroll
      for (int r = 0; r < 16; ++r) {
        int row = (r & 3) + 8 * (r >> 2) + 4 * hi;
        float f = __shfl(al, row, 64);
        o0[r] *= f; o1[r] *= f;
      }
    }

    float ls = 0.f;
    #pragma unroll
    for (int r = 0; r < 16; ++r) { float e = __builtin_amdgcn_exp2f(sA[r] - mr); sA[r] = e; ls += e; }
    #pragma unroll
    for (int r = 0; r < 16; ++r) { float e = __builtin_amdgcn_exp2f(sB[r] - mr); sB[r] = e; ls += e; }
    lsum += ls;

    // ---- pack P to bf16 + lo/hi half exchange -> A-fragments pa[4] ----
    u32 wa[8], wb[8];
    #pragma unroll
    for (int j = 0; j < 8; ++j) {
      wa[j] = cvtpk(sA[2 * j], sA[2 * j + 1]);
      wb[j] = cvtpk(sB[2 * j], sB[2 * j + 1]);
    }
    u32 xa0 = __shfl_xor((int)wa[0], 32), xa1 = __shfl_xor((int)wa[1], 32);
    u32 xa2 = __shfl_xor((int)wa[2], 32), xa3 = __shfl_xor((int)wa[3], 32);
    u32 xa4 = __shfl_xor((int)wa[4], 32), xa5 = __shfl_xor((int)wa[5], 32);
    u32 xa6 = __shfl_xor((int)wa[6], 32), xa7 = __shfl_xor((int)wa[7], 32);
    u32 xb0 = __shfl_xor((int)wb[0], 32), xb1 = __shfl_xor((int)wb[1], 32);
    u32 xb2 = __shfl_xor((int)wb[2], 32), xb3 = __shfl_xor((int)wb[3], 32);
    u32 xb4 = __shfl_xor((int)wb[4], 32), xb5 = __shfl_xor((int)wb[5], 32);
    u32 xb6 = __shfl_xor((int)wb[6], 32), xb7 = __shfl_xor((int)wb[7], 32);
    bf16x8 pa0 = mkfrag(hi ? xa2 : wa[0], hi ? xa3 : wa[1], hi ? wa[2] : xa0, hi ? wa[3] : xa1);
    bf16x8 pa1 = mkfrag(hi ? xa6 : wa[4], hi ? xa7 : wa[5], hi ? wa[6] : xa4, hi ? wa[7] : xa5);
    bf16x8 pa2 = mkfrag(hi ? xb2 : wb[0], hi ? xb3 : wb[1], hi ? wb[2] : xb0, hi ? wb[3] : xb1);
    bf16x8 pa3 = mkfrag(hi ? xb6 : wb[4], hi ? xb7 : wb[5], hi ? wb[6] : xb4, hi ? wb[7] : xb5);

    // ---- O += P * V ----
    __builtin_amdgcn_s_setprio(1);
    #pragma unroll
    for (int ks = 0; ks < 4; ++ks) {
      bf16x8 pf = (ks == 0) ? pa0 : (ks == 1) ? pa1 : (ks == 2) ? pa2 : pa3;
      bf16x8 vf0 = *(const bf16x8*)((const char*)Vs[cur] + (((lq) * 128 + ks * 32 + hi * 16) ^ swz));
      bf16x8 vf1 = *(const bf16x8*)((const char*)Vs[cur] + (((32 + lq) * 128 + ks * 32 + hi * 16) ^ swz));
      o0 = __builtin_amdgcn_mfma_f32_32x32x16_bf16(pf, vf0, o0, 0, 0, 0);
      o1 = __builtin_amdgcn_mfma_f32_32x32x16_bf16(pf, vf1, o1, 0, 0, 0);
    }
    __builtin_amdgcn_s_setprio(0);

    __builtin_amdgcn_s_barrier();
  }
  #undef STAGE

  // ---- epilogue: divide by row-sum, coalesced bf16 stores ----
  lsum += __shfl_xor(lsum, 32);
  const int b = bh >> 4, h = bh & 15;
  u16* aob = ao + (u32)(b * 1024 + qb * 128 + w * 32) * 1024 + h * 64;
  #pragma unroll
  for (int r = 0; r < 16; ++r) {
    int row = (r & 3) + 8 * (r >> 2) + 4 * hi;
    float inv = 1.0f / __shfl(lsum, row, 64);
    aob[row * 1024 + lq]      = f2bf(o0[r] * inv);
    aob[row * 1024 + 32 + lq] = f2bf(o1[r] * inv);
  }
}

// ---------------- launch ----------------
extern "C" void kernel_launch(void* const* d_in, const int* in_sizes, int n_in,
                              void* d_out, int out_size, void* d_ws, size_t ws_size,
                              hipStream_t stream) {
  const float* x      = (const float*)d_in[0];
  const float* w_qkv  = (const float*)d_in[1];
  const float* b_qkv  = (const float*)d_in[2];
  const float* w_proj = (const float*)d_in[3];
  const float* b_proj = (const float*)d_in[4];
  float* out = (float*)d_out;
  char* ws = (char*)d_ws;

  u16* X16   = (u16*)ws;                   //  [4096][1024] bf16 (reused as AO later)
  u16* Wqkv  = (u16*)(ws + 8388608);       //  [3072][1024] bf16
  u16* Wproj = (u16*)(ws + 14680064);      //  [1024][1024] bf16
  u16* Q     = (u16*)(ws + 16777216);      //  [64][1024][64]
  u16* K     = (u16*)(ws + 25165824);      //  [64][1024][64]
  u16* VT    = (u16*)(ws + 33554432);      //  [64][64][1024]
  u16* AO    = X16;

  k_cvt_x<<<dim3(2048), dim3(256), 0, stream>>>(x, X16);
  k_transpose_cvt<<<dim3(96, 32), dim3(32, 8), 0, stream>>>(w_qkv, Wqkv, 1024, 3072);
  k_transpose_cvt<<<dim3(32, 32), dim3(32, 8), 0, stream>>>(w_proj, Wproj, 1024, 1024);
  k_gemm<1, 24><<<dim3(768), dim3(512), 0, stream>>>(X16, Wqkv, b_qkv, Q, K, VT, (float*)0);
  k_attn<<<dim3(512), dim3(256), 0, stream>>>(Q, K, VT, AO);
  k_gemm<0, 8><<<dim3(256), dim3(512), 0, stream>>>(AO, Wproj, b_proj, (u16*)0, (u16*)0, (u16*)0, out);
}